// Round 1
// baseline (2129.380 us; speedup 1.0000x reference)
//
#include <hip/hip_runtime.h>
#include <hip/hip_bf16.h>

#define E_ 64
#define S_ 64
#define N_ 4096      // E*S
#define VOBS 128
#define KOBS 32
#define H_ 256
#define L_ 32
#define VCOMM 32

typedef __attribute__((ext_vector_type(8))) short short8;
typedef __attribute__((ext_vector_type(4))) float floatx4;

__device__ __forceinline__ float prelu_f(float x, float a){ return x >= 0.f ? x : a*x; }
__device__ __forceinline__ ushort f2bf(float x){
  unsigned int u = __float_as_uint(x);
  u = (u + 0x7FFFu + ((u >> 16) & 1u)) >> 16;
  return (ushort)u;
}
__device__ __forceinline__ float sigmoid_f(float x){ return 1.f/(1.f + expf(-x)); }

// ---------------- obs path ----------------

__global__ void k_idx(const float* __restrict__ obs, int* __restrict__ idx){
  int n = blockIdx.x*blockDim.x + threadIdx.x;
  if (n >= N_) return;
  int cnt = 0;
  for (int j = 0; j < VOBS; ++j){
    float v = obs[(size_t)n*VOBS + j];
    if (v > 0.5f){ if (cnt < KOBS) idx[n*KOBS + cnt] = j; ++cnt; }
  }
  for (int c = cnt; c < KOBS; ++c) idx[n*KOBS + c] = 0;
}

// contrib[v][k][h] = sum_j prelu(obs_emb[v][j]) * obs_W[(k*H+j)*H + h]
__global__ __launch_bounds__(256) void k_contrib(
    const float* __restrict__ obs_emb, const float* __restrict__ a_emb_p,
    const float* __restrict__ obs_W, float* __restrict__ contrib){
  const int k = blockIdx.x;          // 0..31
  const int vbase = blockIdx.y*16;   // 0,16,...,112
  const int tid = threadIdx.x;       // h
  __shared__ float pe[16][H_];
  float a = a_emb_p[0];
  for (int i = tid; i < 16*H_; i += 256){
    int v = i >> 8, j = i & 255;
    pe[v][j] = prelu_f(obs_emb[(size_t)(vbase+v)*H_ + j], a);
  }
  __syncthreads();
  float acc[16];
  #pragma unroll
  for (int v = 0; v < 16; ++v) acc[v] = 0.f;
  for (int j = 0; j < H_; ++j){
    float w = obs_W[((size_t)(k*H_ + j))*H_ + tid];
    #pragma unroll
    for (int v = 0; v < 16; ++v) acc[v] += pe[v][j]*w;
  }
  for (int v = 0; v < 16; ++v)
    contrib[((size_t)((vbase+v)*KOBS + k))*H_ + tid] = acc[v];
}

__global__ __launch_bounds__(256) void k_obs_o(
    const int* __restrict__ idx, const float* __restrict__ contrib,
    const float* __restrict__ obs_b, const float* __restrict__ obs_a_p,
    float* __restrict__ out){
  const int n = blockIdx.x, tid = threadIdx.x;
  __shared__ int id[KOBS];
  if (tid < KOBS) id[tid] = idx[n*KOBS + tid];
  __syncthreads();
  float acc = obs_b[tid];
  #pragma unroll 8
  for (int k = 0; k < KOBS; ++k)
    acc += contrib[((size_t)(id[k]*KOBS + k))*H_ + tid];
  out[(size_t)n*512 + tid] = prelu_f(acc, obs_a_p[0]);
}

// ---------------- comm path ----------------

__global__ void k_tok(const float* __restrict__ comm, int* __restrict__ tok){
  int i = blockIdx.x*blockDim.x + threadIdx.x; // (n,l) flat, 0..131071
  if (i >= N_*L_) return;
  const float* p = comm + (size_t)i*VCOMM;
  float best = p[0]; int bi = 0;
  for (int j = 1; j < VCOMM; ++j){ float v = p[j]; if (v > best){ best = v; bi = j; } }
  tok[i] = bi;
}

// P[slot][v][c] = sum_h prelu(comm_emb[v][h]) * w_g[c][h][tap]
__global__ void k_P(const float* __restrict__ comm_emb, const float* __restrict__ ca_p,
                    const float* __restrict__ cw1, const float* __restrict__ cw3,
                    const float* __restrict__ cw5, const float* __restrict__ cw7,
                    float* __restrict__ P){
  const int slot = blockIdx.x, v = blockIdx.y, c = threadIdx.x;
  int g, tap;
  if (slot == 0){ g=0; tap=0; }
  else if (slot < 4){ g=1; tap=slot-1; }
  else if (slot < 9){ g=2; tap=slot-4; }
  else { g=3; tap=slot-9; }
  const float* w; int ks;
  if (g==0){ w=cw1; ks=1; } else if (g==1){ w=cw3; ks=3; }
  else if (g==2){ w=cw5; ks=5; } else { w=cw7; ks=7; }
  float a = ca_p[0];
  float acc = 0.f;
  for (int h = 0; h < H_; ++h){
    float e = prelu_f(comm_emb[(size_t)v*H_ + h], a);
    acc += e * w[(size_t)(c*H_ + h)*ks + tap];
  }
  P[(size_t)(slot*VCOMM + v)*64 + c] = acc;
}

// block handles 16 n; thread tid = c_out (g = tid>>6, c = tid&63)
__global__ __launch_bounds__(256) void k_conv_stats(
    const int* __restrict__ tok, const float* __restrict__ P,
    const float* __restrict__ cb1, const float* __restrict__ cb3,
    const float* __restrict__ cb5, const float* __restrict__ cb7,
    float* __restrict__ stats){
  const int nbase = blockIdx.x*16, tid = threadIdx.x;
  const int g = tid >> 6, c = tid & 63;
  const int ks = 2*g + 1, pad = g, base = g*g;
  const float* cb = (g==0)?cb1:(g==1)?cb3:(g==2)?cb5:cb7;
  const float bias = cb[c];
  __shared__ int tk[16][L_];
  for (int i = tid; i < 16*L_; i += 256)
    tk[i>>5][i&31] = tok[(size_t)(nbase + (i>>5))*L_ + (i&31)];
  __syncthreads();
  float s = 0.f, sq = 0.f;
  for (int nn = 0; nn < 16; ++nn){
    for (int l = 0; l < L_; ++l){
      float acc = bias;
      for (int t = 0; t < ks; ++t){
        int lp = l + t - pad;
        if (lp >= 0 && lp < L_)
          acc += P[(size_t)((base + t)*VCOMM + tk[nn][lp])*64 + c];
      }
      s += acc; sq += acc*acc;
    }
  }
  atomicAdd(&stats[tid], s);
  atomicAdd(&stats[256 + tid], sq);
}

__global__ void k_bn_fin(const float* __restrict__ stats, const float* __restrict__ bn_g,
                         const float* __restrict__ bn_b, float* __restrict__ ss){
  int t = threadIdx.x;
  const float cnt = (float)(N_*L_);
  float m = stats[t]/cnt;
  float v = stats[256+t]/cnt - m*m;
  float sc = bn_g[t] / sqrtf(v + 1e-5f);
  ss[t] = sc; ss[256+t] = bn_b[t] - m*sc;
}

// recompute conv, apply BN+prelu, write ynorm bf16 [L][N][H]
__global__ __launch_bounds__(256) void k_conv_apply(
    const int* __restrict__ tok, const float* __restrict__ P,
    const float* __restrict__ cb1, const float* __restrict__ cb3,
    const float* __restrict__ cb5, const float* __restrict__ cb7,
    const float* __restrict__ ss, const float* __restrict__ cnn_a_p,
    ushort* __restrict__ ynorm){
  const int nbase = blockIdx.x*16, tid = threadIdx.x;
  const int g = tid >> 6, c = tid & 63;
  const int ks = 2*g + 1, pad = g, base = g*g;
  const float* cb = (g==0)?cb1:(g==1)?cb3:(g==2)?cb5:cb7;
  const float bias = cb[c];
  const float scale = ss[tid], shift = ss[256+tid], ca = cnn_a_p[0];
  __shared__ int tk[16][L_];
  for (int i = tid; i < 16*L_; i += 256)
    tk[i>>5][i&31] = tok[(size_t)(nbase + (i>>5))*L_ + (i&31)];
  __syncthreads();
  for (int nn = 0; nn < 16; ++nn){
    for (int l = 0; l < L_; ++l){
      float acc = bias;
      for (int t = 0; t < ks; ++t){
        int lp = l + t - pad;
        if (lp >= 0 && lp < L_)
          acc += P[(size_t)((base + t)*VCOMM + tk[nn][lp])*64 + c];
      }
      float y = fmaf(acc, scale, shift);
      y = prelu_f(y, ca);
      ynorm[((size_t)l*N_ + (nbase+nn))*H_ + tid] = f2bf(y);
    }
  }
}

// ---------------- GRU scan ----------------

// WT[c][k] bf16, c in [0,1024), k in [0,512)
__global__ void k_WT(const float* __restrict__ Wx, const float* __restrict__ Wh,
                     ushort* __restrict__ WT){
  int id = blockIdx.x*blockDim.x + threadIdx.x;  // 0..524287
  int c = id >> 9, k = id & 511;
  int chunk = c >> 8, u = c & 255;
  float val = 0.f;
  if (chunk == 0)      val = (k<256) ? Wx[(size_t)(k)*256 + u]       : Wh[(size_t)(k-256)*256 + u];
  else if (chunk == 1) val = (k<256) ? Wx[(size_t)(256+k)*256 + u]   : Wh[(size_t)(256+(k-256))*256 + u];
  else if (chunk == 2) val = (k<256) ? Wx[(size_t)(512+k)*256 + u]   : 0.f;
  else                 val = (k<256) ? 0.f : Wh[(size_t)(512+(k-256))*256 + u];
  WT[id] = f2bf(val);
}

// GEMM: out[4096][1024] = [ynorm_l | hbf] (bf16, [4096][512]) x WT^T
// BM=128, BN=64, BK=32; grid (32, 16), 256 threads = 4 waves (2x2), wave tile 64x32
__global__ __launch_bounds__(256) void k_step_gemm(
    const ushort* __restrict__ Ay, const ushort* __restrict__ Ah,
    const ushort* __restrict__ WT, float* __restrict__ out)
{
  const int bm = blockIdx.x, bn = blockIdx.y;
  const int tid = threadIdx.x;
  const int lane = tid & 63;
  const int wave = tid >> 6;
  const int wm = wave >> 1, wn = wave & 1;
  const int quad = lane >> 4, l16 = lane & 15;

  __shared__ __align__(16) ushort As[128][40];
  __shared__ __align__(16) ushort Bs[64][40];

  floatx4 acc[4][2];
  #pragma unroll
  for (int i = 0; i < 4; ++i)
    #pragma unroll
    for (int j = 0; j < 2; ++j)
      acc[i][j] = (floatx4){0.f,0.f,0.f,0.f};

  for (int kt = 0; kt < 16; ++kt){
    const ushort* Aptr = (kt < 8) ? (Ay + (size_t)bm*128*H_ + kt*32)
                                  : (Ah + (size_t)bm*128*H_ + (kt-8)*32);
    const ushort* Bptr = WT + (size_t)bn*64*512 + kt*32;
    __syncthreads();
    // A tile: 128 rows x 32 k = 512 chunks of 8
    #pragma unroll
    for (int c0 = 0; c0 < 2; ++c0){
      int chunk = c0*256 + tid;
      int row = chunk >> 2, kc = chunk & 3;
      uint4 va = *(const uint4*)(Aptr + (size_t)row*H_ + kc*8);
      *(uint4*)&As[row][kc*8] = va;
    }
    // B tile: 64 rows x 32 k = 256 chunks
    {
      int row = tid >> 2, kc = tid & 3;
      uint4 vb = *(const uint4*)(Bptr + (size_t)row*512 + kc*8);
      *(uint4*)&Bs[row][kc*8] = vb;
    }
    __syncthreads();
    short8 a[4], b[2];
    #pragma unroll
    for (int mi = 0; mi < 4; ++mi)
      a[mi] = *(const short8*)&As[wm*64 + mi*16 + l16][quad*8];
    #pragma unroll
    for (int ni = 0; ni < 2; ++ni)
      b[ni] = *(const short8*)&Bs[wn*32 + ni*16 + l16][quad*8];
    #pragma unroll
    for (int mi = 0; mi < 4; ++mi)
      #pragma unroll
      for (int ni = 0; ni < 2; ++ni)
        acc[mi][ni] = __builtin_amdgcn_mfma_f32_16x16x32_bf16(a[mi], b[ni], acc[mi][ni], 0,0,0);
  }
  #pragma unroll
  for (int mi = 0; mi < 4; ++mi){
    #pragma unroll
    for (int ni = 0; ni < 2; ++ni){
      #pragma unroll
      for (int r = 0; r < 4; ++r){
        int row = bm*128 + wm*64 + mi*16 + quad*4 + r;
        int col = bn*64 + wn*32 + ni*16 + l16;
        out[(size_t)row*1024 + col] = acc[mi][ni][r];
      }
    }
  }
}

__global__ void k_gate(const float* __restrict__ gout, const float* __restrict__ bx,
                       const float* __restrict__ bh, float* __restrict__ h,
                       ushort* __restrict__ hbf){
  int id = blockIdx.x*blockDim.x + threadIdx.x; // 0..1048575
  int n = id >> 8, u = id & 255;
  const float* row = gout + (size_t)n*1024;
  float o0 = row[u], o1 = row[256+u], o2 = row[512+u], o3 = row[768+u];
  float r = sigmoid_f(o0 + bx[u] + bh[u]);
  float z = sigmoid_f(o1 + bx[256+u] + bh[256+u]);
  float nn = tanhf(o2 + bx[512+u] + r*(o3 + bh[512+u]));
  float hp = h[id];
  float hv = nn*(1.f - z) + hp*z;
  h[id] = hv;
  hbf[id] = f2bf(hv);
}

// c = prelu(prelu(h,a1) @ lin_W + lin_b, a2) -> out[..., 256:512]
__global__ __launch_bounds__(256) void k_final(
    const float* __restrict__ h, const float* __restrict__ a1p,
    const float* __restrict__ lin_W, const float* __restrict__ lin_b,
    const float* __restrict__ a2p, float* __restrict__ out){
  const int nbase = blockIdx.x*16, tid = threadIdx.x;
  __shared__ float hp[16][H_];
  const float a1 = a1p[0], a2 = a2p[0];
  for (int i = tid; i < 16*H_; i += 256)
    hp[i>>8][i&255] = prelu_f(h[(size_t)(nbase + (i>>8))*H_ + (i&255)], a1);
  __syncthreads();
  float acc[16];
  const float b = lin_b[tid];
  #pragma unroll
  for (int r = 0; r < 16; ++r) acc[r] = b;
  for (int j = 0; j < H_; ++j){
    float w = lin_W[(size_t)j*H_ + tid];
    #pragma unroll
    for (int r = 0; r < 16; ++r) acc[r] += hp[r][j]*w;
  }
  for (int r = 0; r < 16; ++r)
    out[(size_t)(nbase+r)*512 + 256 + tid] = prelu_f(acc[r], a2);
}

extern "C" void kernel_launch(void* const* d_in, const int* in_sizes, int n_in,
                              void* d_out, int out_size, void* d_ws, size_t ws_size,
                              hipStream_t stream) {
  (void)in_sizes; (void)n_in; (void)out_size; (void)ws_size;
  const float* obs      = (const float*)d_in[0];
  const float* comm     = (const float*)d_in[1];
  const float* obs_emb  = (const float*)d_in[2];
  const float* obs_a_emb= (const float*)d_in[3];
  const float* obs_W    = (const float*)d_in[4];
  const float* obs_b    = (const float*)d_in[5];
  const float* obs_a    = (const float*)d_in[6];
  const float* comm_emb = (const float*)d_in[7];
  const float* comm_a   = (const float*)d_in[8];
  const float* cw1      = (const float*)d_in[9];
  const float* cb1      = (const float*)d_in[10];
  const float* cw3      = (const float*)d_in[11];
  const float* cb3      = (const float*)d_in[12];
  const float* cw5      = (const float*)d_in[13];
  const float* cb5      = (const float*)d_in[14];
  const float* cw7      = (const float*)d_in[15];
  const float* cb7      = (const float*)d_in[16];
  const float* bn_g     = (const float*)d_in[17];
  const float* bn_b     = (const float*)d_in[18];
  const float* cnn_a    = (const float*)d_in[19];
  const float* Wx       = (const float*)d_in[20];
  const float* bx       = (const float*)d_in[21];
  const float* Wh       = (const float*)d_in[22];
  const float* bh       = (const float*)d_in[23];
  const float* lin_a1   = (const float*)d_in[24];
  const float* lin_W    = (const float*)d_in[25];
  const float* lin_b    = (const float*)d_in[26];
  const float* lin_a2   = (const float*)d_in[27];
  float* out = (float*)d_out;

  char* ws = (char*)d_ws;
  float*  contrib = (float*)(ws + 0);            // 4,194,304
  float*  P       = (float*)(ws + 4194304);      // 131,072
  int*    idx     = (int*)  (ws + 4325376);      // 524,288
  int*    tok     = (int*)  (ws + 4849664);      // 524,288
  float*  stats   = (float*)(ws + 5373952);      // 2,048
  float*  ss      = (float*)(ws + 5376000);      // 2,048
  ushort* WT      = (ushort*)(ws + 5378048);     // 1,048,576
  float*  h       = (float*)(ws + 6426624);      // 4,194,304
  ushort* hbf     = (ushort*)(ws + 10620928);    // 2,097,152
  float*  gout    = (float*)(ws + 12718080);     // 16,777,216
  ushort* ynorm   = (ushort*)(ws + 29495296);    // 67,108,864

  hipMemsetAsync(stats, 0, 512*sizeof(float), stream);
  hipMemsetAsync(h, 0, (size_t)N_*H_*sizeof(float), stream);
  hipMemsetAsync(hbf, 0, (size_t)N_*H_*sizeof(ushort), stream);

  k_idx<<<16, 256, 0, stream>>>(obs, idx);
  k_tok<<<512, 256, 0, stream>>>(comm, tok);
  k_WT<<<2048, 256, 0, stream>>>(Wx, Wh, WT);
  k_P<<<dim3(16,32), 64, 0, stream>>>(comm_emb, comm_a, cw1, cw3, cw5, cw7, P);
  k_contrib<<<dim3(32,8), 256, 0, stream>>>(obs_emb, obs_a_emb, obs_W, contrib);
  k_obs_o<<<4096, 256, 0, stream>>>(idx, contrib, obs_b, obs_a, out);
  k_conv_stats<<<256, 256, 0, stream>>>(tok, P, cb1, cb3, cb5, cb7, stats);
  k_bn_fin<<<1, 256, 0, stream>>>(stats, bn_g, bn_b, ss);
  k_conv_apply<<<256, 256, 0, stream>>>(tok, P, cb1, cb3, cb5, cb7, ss, cnn_a, ynorm);

  for (int l = 0; l < L_; ++l){
    k_step_gemm<<<dim3(32,16), 256, 0, stream>>>(ynorm + (size_t)l*N_*H_, hbf, WT, gout);
    k_gate<<<4096, 256, 0, stream>>>(gout, bx, bh, h, hbf);
  }
  k_final<<<256, 256, 0, stream>>>(h, lin_a1, lin_W, lin_b, lin_a2, out);
}

// Round 2
// 1262.903 us; speedup vs baseline: 1.6861x; 1.6861x over previous
//
#include <hip/hip_runtime.h>
#include <hip/hip_bf16.h>

#define E_ 64
#define S_ 64
#define N_ 4096      // E*S
#define VOBS 128
#define KOBS 32
#define H_ 256
#define L_ 32
#define VCOMM 32

typedef __attribute__((ext_vector_type(8))) short short8;
typedef __attribute__((ext_vector_type(4))) float floatx4;

__device__ __forceinline__ float prelu_f(float x, float a){ return x >= 0.f ? x : a*x; }
__device__ __forceinline__ ushort f2bf(float x){
  unsigned int u = __float_as_uint(x);
  u = (u + 0x7FFFu + ((u >> 16) & 1u)) >> 16;
  return (ushort)u;
}
__device__ __forceinline__ float sigmoid_f(float x){ return 1.f/(1.f + expf(-x)); }

// ---------------- obs path ----------------

__global__ void k_idx(const float* __restrict__ obs, int* __restrict__ idx){
  int n = blockIdx.x*blockDim.x + threadIdx.x;
  if (n >= N_) return;
  int cnt = 0;
  for (int j = 0; j < VOBS; ++j){
    float v = obs[(size_t)n*VOBS + j];
    if (v > 0.5f){ if (cnt < KOBS) idx[n*KOBS + cnt] = j; ++cnt; }
  }
  for (int c = cnt; c < KOBS; ++c) idx[n*KOBS + c] = 0;
}

// contrib[v][k][h] = sum_j prelu(obs_emb[v][j]) * obs_W[(k*H+j)*H + h]
__global__ __launch_bounds__(256) void k_contrib(
    const float* __restrict__ obs_emb, const float* __restrict__ a_emb_p,
    const float* __restrict__ obs_W, float* __restrict__ contrib){
  const int k = blockIdx.x;          // 0..31
  const int vbase = blockIdx.y*16;   // 0,16,...,112
  const int tid = threadIdx.x;       // h
  __shared__ float pe[16][H_];
  float a = a_emb_p[0];
  for (int i = tid; i < 16*H_; i += 256){
    int v = i >> 8, j = i & 255;
    pe[v][j] = prelu_f(obs_emb[(size_t)(vbase+v)*H_ + j], a);
  }
  __syncthreads();
  float acc[16];
  #pragma unroll
  for (int v = 0; v < 16; ++v) acc[v] = 0.f;
  for (int j = 0; j < H_; ++j){
    float w = obs_W[((size_t)(k*H_ + j))*H_ + tid];
    #pragma unroll
    for (int v = 0; v < 16; ++v) acc[v] += pe[v][j]*w;
  }
  for (int v = 0; v < 16; ++v)
    contrib[((size_t)((vbase+v)*KOBS + k))*H_ + tid] = acc[v];
}

__global__ __launch_bounds__(256) void k_obs_o(
    const int* __restrict__ idx, const float* __restrict__ contrib,
    const float* __restrict__ obs_b, const float* __restrict__ obs_a_p,
    float* __restrict__ out){
  const int n = blockIdx.x, tid = threadIdx.x;
  __shared__ int id[KOBS];
  if (tid < KOBS) id[tid] = idx[n*KOBS + tid];
  __syncthreads();
  float acc = obs_b[tid];
  #pragma unroll 8
  for (int k = 0; k < KOBS; ++k)
    acc += contrib[((size_t)(id[k]*KOBS + k))*H_ + tid];
  out[(size_t)n*512 + tid] = prelu_f(acc, obs_a_p[0]);
}

// ---------------- comm path ----------------

__global__ void k_tok(const float* __restrict__ comm, int* __restrict__ tok){
  int i = blockIdx.x*blockDim.x + threadIdx.x; // (n,l) flat, 0..131071
  if (i >= N_*L_) return;
  const float* p = comm + (size_t)i*VCOMM;
  float best = p[0]; int bi = 0;
  for (int j = 1; j < VCOMM; ++j){ float v = p[j]; if (v > best){ best = v; bi = j; } }
  tok[i] = bi;
}

// P[slot][v][c] = sum_h prelu(comm_emb[v][h]) * w_g[c][h][tap]
__global__ void k_P(const float* __restrict__ comm_emb, const float* __restrict__ ca_p,
                    const float* __restrict__ cw1, const float* __restrict__ cw3,
                    const float* __restrict__ cw5, const float* __restrict__ cw7,
                    float* __restrict__ P){
  const int slot = blockIdx.x, v = blockIdx.y, c = threadIdx.x;
  int g, tap;
  if (slot == 0){ g=0; tap=0; }
  else if (slot < 4){ g=1; tap=slot-1; }
  else if (slot < 9){ g=2; tap=slot-4; }
  else { g=3; tap=slot-9; }
  const float* w; int ks;
  if (g==0){ w=cw1; ks=1; } else if (g==1){ w=cw3; ks=3; }
  else if (g==2){ w=cw5; ks=5; } else { w=cw7; ks=7; }
  float a = ca_p[0];
  float acc = 0.f;
  for (int h = 0; h < H_; ++h){
    float e = prelu_f(comm_emb[(size_t)v*H_ + h], a);
    acc += e * w[(size_t)(c*H_ + h)*ks + tap];
  }
  P[(size_t)(slot*VCOMM + v)*64 + c] = acc;
}

// Conv passes restructured: grid (256 n-chunks, 4 groups). Block stages its
// group's P-slice ((2g+1)*32*64 floats, <=57KB) + 16x32 token tile into LDS.
// Wave layout: lane = channel c within group; each wave walks 128 (nn,l)
// pairs (wave-uniform t,v -> conflict-free 2-way LDS reads).
__global__ __launch_bounds__(256) void k_conv_stats(
    const int* __restrict__ tok, const float* __restrict__ P,
    const float* __restrict__ cb1, const float* __restrict__ cb3,
    const float* __restrict__ cb5, const float* __restrict__ cb7,
    float* __restrict__ stats){
  const int g = blockIdx.y;
  const int nbase = blockIdx.x*16;
  const int tid = threadIdx.x, lane = tid & 63, wave = tid >> 6;
  const int ks = 2*g + 1, pad = g, base = g*g;
  const float* cb = (g==0)?cb1:(g==1)?cb3:(g==2)?cb5:cb7;
  const float bias = cb[lane];
  __shared__ float Ps[7*2048];
  __shared__ int tk[16][L_];
  __shared__ float red_s[4][64], red_q[4][64];
  for (int i = tid; i < ks*2048; i += 256) Ps[i] = P[base*2048 + i];
  for (int i = tid; i < 16*L_; i += 256)
    tk[i>>5][i&31] = tok[(size_t)(nbase + (i>>5))*L_ + (i&31)];
  __syncthreads();
  float s = 0.f, sq = 0.f;
  for (int p = wave*128; p < wave*128 + 128; ++p){
    const int nn = p >> 5, l = p & 31;
    float acc = bias;
    for (int t = 0; t < ks; ++t){
      int lp = l + t - pad;
      if ((unsigned)lp < (unsigned)L_)
        acc += Ps[t*2048 + tk[nn][lp]*64 + lane];
    }
    s += acc; sq += acc*acc;
  }
  red_s[wave][lane] = s; red_q[wave][lane] = sq;
  __syncthreads();
  if (wave == 0){
    float ts = red_s[0][lane]+red_s[1][lane]+red_s[2][lane]+red_s[3][lane];
    float tq = red_q[0][lane]+red_q[1][lane]+red_q[2][lane]+red_q[3][lane];
    atomicAdd(&stats[g*64 + lane], ts);
    atomicAdd(&stats[256 + g*64 + lane], tq);
  }
}

__global__ void k_bn_fin(const float* __restrict__ stats, const float* __restrict__ bn_g,
                         const float* __restrict__ bn_b, float* __restrict__ ss){
  int t = threadIdx.x;
  const float cnt = (float)(N_*L_);
  float m = stats[t]/cnt;
  float v = stats[256+t]/cnt - m*m;
  float sc = bn_g[t] / sqrtf(v + 1e-5f);
  ss[t] = sc; ss[256+t] = bn_b[t] - m*sc;
}

// recompute conv, apply BN+prelu, write ynorm bf16 [L][N][H]
__global__ __launch_bounds__(256) void k_conv_apply(
    const int* __restrict__ tok, const float* __restrict__ P,
    const float* __restrict__ cb1, const float* __restrict__ cb3,
    const float* __restrict__ cb5, const float* __restrict__ cb7,
    const float* __restrict__ ss, const float* __restrict__ cnn_a_p,
    ushort* __restrict__ ynorm){
  const int g = blockIdx.y;
  const int nbase = blockIdx.x*16;
  const int tid = threadIdx.x, lane = tid & 63, wave = tid >> 6;
  const int ks = 2*g + 1, pad = g, base = g*g;
  const float* cb = (g==0)?cb1:(g==1)?cb3:(g==2)?cb5:cb7;
  const float bias = cb[lane];
  const float scale = ss[g*64 + lane], shift = ss[256 + g*64 + lane];
  const float ca = cnn_a_p[0];
  __shared__ float Ps[7*2048];
  __shared__ int tk[16][L_];
  for (int i = tid; i < ks*2048; i += 256) Ps[i] = P[base*2048 + i];
  for (int i = tid; i < 16*L_; i += 256)
    tk[i>>5][i&31] = tok[(size_t)(nbase + (i>>5))*L_ + (i&31)];
  __syncthreads();
  for (int p = wave*128; p < wave*128 + 128; ++p){
    const int nn = p >> 5, l = p & 31;
    float acc = bias;
    for (int t = 0; t < ks; ++t){
      int lp = l + t - pad;
      if ((unsigned)lp < (unsigned)L_)
        acc += Ps[t*2048 + tk[nn][lp]*64 + lane];
    }
    float y = prelu_f(fmaf(acc, scale, shift), ca);
    ynorm[((size_t)l*N_ + (nbase+nn))*H_ + g*64 + lane] = f2bf(y);
  }
}

// ---------------- GRU scan ----------------

// WT[c][k] bf16, c in [0,1024), k in [0,512)
__global__ void k_WT(const float* __restrict__ Wx, const float* __restrict__ Wh,
                     ushort* __restrict__ WT){
  int id = blockIdx.x*blockDim.x + threadIdx.x;  // 0..524287
  int c = id >> 9, k = id & 511;
  int chunk = c >> 8, u = c & 255;
  float val = 0.f;
  if (chunk == 0)      val = (k<256) ? Wx[(size_t)(k)*256 + u]       : Wh[(size_t)(k-256)*256 + u];
  else if (chunk == 1) val = (k<256) ? Wx[(size_t)(256+k)*256 + u]   : Wh[(size_t)(256+(k-256))*256 + u];
  else if (chunk == 2) val = (k<256) ? Wx[(size_t)(512+k)*256 + u]   : 0.f;
  else                 val = (k<256) ? 0.f : Wh[(size_t)(512+(k-256))*256 + u];
  WT[id] = f2bf(val);
}

// GEMM: out[4096][1024] = [ynorm_l | hbf] (bf16, [4096][512]) x WT^T
// BM=128, BN=64, BK=32; grid (32, 16), 256 threads = 4 waves (2x2), wave tile 64x32
__global__ __launch_bounds__(256) void k_step_gemm(
    const ushort* __restrict__ Ay, const ushort* __restrict__ Ah,
    const ushort* __restrict__ WT, float* __restrict__ out)
{
  const int bm = blockIdx.x, bn = blockIdx.y;
  const int tid = threadIdx.x;
  const int lane = tid & 63;
  const int wave = tid >> 6;
  const int wm = wave >> 1, wn = wave & 1;
  const int quad = lane >> 4, l16 = lane & 15;

  __shared__ __align__(16) ushort As[128][40];
  __shared__ __align__(16) ushort Bs[64][40];

  floatx4 acc[4][2];
  #pragma unroll
  for (int i = 0; i < 4; ++i)
    #pragma unroll
    for (int j = 0; j < 2; ++j)
      acc[i][j] = (floatx4){0.f,0.f,0.f,0.f};

  for (int kt = 0; kt < 16; ++kt){
    const ushort* Aptr = (kt < 8) ? (Ay + (size_t)bm*128*H_ + kt*32)
                                  : (Ah + (size_t)bm*128*H_ + (kt-8)*32);
    const ushort* Bptr = WT + (size_t)bn*64*512 + kt*32;
    __syncthreads();
    // A tile: 128 rows x 32 k = 512 chunks of 8
    #pragma unroll
    for (int c0 = 0; c0 < 2; ++c0){
      int chunk = c0*256 + tid;
      int row = chunk >> 2, kc = chunk & 3;
      uint4 va = *(const uint4*)(Aptr + (size_t)row*H_ + kc*8);
      *(uint4*)&As[row][kc*8] = va;
    }
    // B tile: 64 rows x 32 k = 256 chunks
    {
      int row = tid >> 2, kc = tid & 3;
      uint4 vb = *(const uint4*)(Bptr + (size_t)row*512 + kc*8);
      *(uint4*)&Bs[row][kc*8] = vb;
    }
    __syncthreads();
    short8 a[4], b[2];
    #pragma unroll
    for (int mi = 0; mi < 4; ++mi)
      a[mi] = *(const short8*)&As[wm*64 + mi*16 + l16][quad*8];
    #pragma unroll
    for (int ni = 0; ni < 2; ++ni)
      b[ni] = *(const short8*)&Bs[wn*32 + ni*16 + l16][quad*8];
    #pragma unroll
    for (int mi = 0; mi < 4; ++mi)
      #pragma unroll
      for (int ni = 0; ni < 2; ++ni)
        acc[mi][ni] = __builtin_amdgcn_mfma_f32_16x16x32_bf16(a[mi], b[ni], acc[mi][ni], 0,0,0);
  }
  #pragma unroll
  for (int mi = 0; mi < 4; ++mi){
    #pragma unroll
    for (int ni = 0; ni < 2; ++ni){
      #pragma unroll
      for (int r = 0; r < 4; ++r){
        int row = bm*128 + wm*64 + mi*16 + quad*4 + r;
        int col = bn*64 + wn*32 + ni*16 + l16;
        out[(size_t)row*1024 + col] = acc[mi][ni][r];
      }
    }
  }
}

__global__ void k_gate(const float* __restrict__ gout, const float* __restrict__ bx,
                       const float* __restrict__ bh, float* __restrict__ h,
                       ushort* __restrict__ hbf){
  int id = blockIdx.x*blockDim.x + threadIdx.x; // 0..1048575
  int n = id >> 8, u = id & 255;
  const float* row = gout + (size_t)n*1024;
  float o0 = row[u], o1 = row[256+u], o2 = row[512+u], o3 = row[768+u];
  float r = sigmoid_f(o0 + bx[u] + bh[u]);
  float z = sigmoid_f(o1 + bx[256+u] + bh[256+u]);
  float nn = tanhf(o2 + bx[512+u] + r*(o3 + bh[512+u]));
  float hp = h[id];
  float hv = nn*(1.f - z) + hp*z;
  h[id] = hv;
  hbf[id] = f2bf(hv);
}

// c = prelu(prelu(h,a1) @ lin_W + lin_b, a2) -> out[..., 256:512]
__global__ __launch_bounds__(256) void k_final(
    const float* __restrict__ h, const float* __restrict__ a1p,
    const float* __restrict__ lin_W, const float* __restrict__ lin_b,
    const float* __restrict__ a2p, float* __restrict__ out){
  const int nbase = blockIdx.x*16, tid = threadIdx.x;
  __shared__ float hp[16][H_];
  const float a1 = a1p[0], a2 = a2p[0];
  for (int i = tid; i < 16*H_; i += 256)
    hp[i>>8][i&255] = prelu_f(h[(size_t)(nbase + (i>>8))*H_ + (i&255)], a1);
  __syncthreads();
  float acc[16];
  const float b = lin_b[tid];
  #pragma unroll
  for (int r = 0; r < 16; ++r) acc[r] = b;
  for (int j = 0; j < H_; ++j){
    float w = lin_W[(size_t)j*H_ + tid];
    #pragma unroll
    for (int r = 0; r < 16; ++r) acc[r] += hp[r][j]*w;
  }
  for (int r = 0; r < 16; ++r)
    out[(size_t)(nbase+r)*512 + 256 + tid] = prelu_f(acc[r], a2);
}

extern "C" void kernel_launch(void* const* d_in, const int* in_sizes, int n_in,
                              void* d_out, int out_size, void* d_ws, size_t ws_size,
                              hipStream_t stream) {
  (void)in_sizes; (void)n_in; (void)out_size; (void)ws_size;
  const float* obs      = (const float*)d_in[0];
  const float* comm     = (const float*)d_in[1];
  const float* obs_emb  = (const float*)d_in[2];
  const float* obs_a_emb= (const float*)d_in[3];
  const float* obs_W    = (const float*)d_in[4];
  const float* obs_b    = (const float*)d_in[5];
  const float* obs_a    = (const float*)d_in[6];
  const float* comm_emb = (const float*)d_in[7];
  const float* comm_a   = (const float*)d_in[8];
  const float* cw1      = (const float*)d_in[9];
  const float* cb1      = (const float*)d_in[10];
  const float* cw3      = (const float*)d_in[11];
  const float* cb3      = (const float*)d_in[12];
  const float* cw5      = (const float*)d_in[13];
  const float* cb5      = (const float*)d_in[14];
  const float* cw7      = (const float*)d_in[15];
  const float* cb7      = (const float*)d_in[16];
  const float* bn_g     = (const float*)d_in[17];
  const float* bn_b     = (const float*)d_in[18];
  const float* cnn_a    = (const float*)d_in[19];
  const float* Wx       = (const float*)d_in[20];
  const float* bx       = (const float*)d_in[21];
  const float* Wh       = (const float*)d_in[22];
  const float* bh       = (const float*)d_in[23];
  const float* lin_a1   = (const float*)d_in[24];
  const float* lin_W    = (const float*)d_in[25];
  const float* lin_b    = (const float*)d_in[26];
  const float* lin_a2   = (const float*)d_in[27];
  float* out = (float*)d_out;

  char* ws = (char*)d_ws;
  float*  contrib = (float*)(ws + 0);            // 4,194,304
  float*  P       = (float*)(ws + 4194304);      // 131,072
  int*    idx     = (int*)  (ws + 4325376);      // 524,288
  int*    tok     = (int*)  (ws + 4849664);      // 524,288
  float*  stats   = (float*)(ws + 5373952);      // 2,048
  float*  ss      = (float*)(ws + 5376000);      // 2,048
  ushort* WT      = (ushort*)(ws + 5378048);     // 1,048,576
  float*  h       = (float*)(ws + 6426624);      // 4,194,304
  ushort* hbf     = (ushort*)(ws + 10620928);    // 2,097,152
  float*  gout    = (float*)(ws + 12718080);     // 16,777,216
  ushort* ynorm   = (ushort*)(ws + 29495296);    // 67,108,864

  hipMemsetAsync(stats, 0, 512*sizeof(float), stream);
  hipMemsetAsync(h, 0, (size_t)N_*H_*sizeof(float), stream);
  hipMemsetAsync(hbf, 0, (size_t)N_*H_*sizeof(ushort), stream);

  k_idx<<<16, 256, 0, stream>>>(obs, idx);
  k_tok<<<512, 256, 0, stream>>>(comm, tok);
  k_WT<<<2048, 256, 0, stream>>>(Wx, Wh, WT);
  k_P<<<dim3(16,32), 64, 0, stream>>>(comm_emb, comm_a, cw1, cw3, cw5, cw7, P);
  k_contrib<<<dim3(32,8), 256, 0, stream>>>(obs_emb, obs_a_emb, obs_W, contrib);
  k_obs_o<<<4096, 256, 0, stream>>>(idx, contrib, obs_b, obs_a, out);
  k_conv_stats<<<dim3(256,4), 256, 0, stream>>>(tok, P, cb1, cb3, cb5, cb7, stats);
  k_bn_fin<<<1, 256, 0, stream>>>(stats, bn_g, bn_b, ss);
  k_conv_apply<<<dim3(256,4), 256, 0, stream>>>(tok, P, cb1, cb3, cb5, cb7, ss, cnn_a, ynorm);

  for (int l = 0; l < L_; ++l){
    k_step_gemm<<<dim3(32,16), 256, 0, stream>>>(ynorm + (size_t)l*N_*H_, hbf, WT, gout);
    k_gate<<<4096, 256, 0, stream>>>(gout, bx, bh, h, hbf);
  }
  k_final<<<256, 256, 0, stream>>>(h, lin_a1, lin_W, lin_b, lin_a2, out);
}

// Round 3
// 884.208 us; speedup vs baseline: 2.4082x; 1.4283x over previous
//
#include <hip/hip_runtime.h>
#include <hip/hip_bf16.h>

#define E_ 64
#define S_ 64
#define N_ 4096      // E*S
#define VOBS 128
#define KOBS 32
#define H_ 256
#define L_ 32
#define VCOMM 32

typedef __attribute__((ext_vector_type(8))) short short8;
typedef __attribute__((ext_vector_type(4))) float floatx4;

__device__ __forceinline__ float prelu_f(float x, float a){ return x >= 0.f ? x : a*x; }
__device__ __forceinline__ ushort f2bf(float x){
  unsigned int u = __float_as_uint(x);
  u = (u + 0x7FFFu + ((u >> 16) & 1u)) >> 16;
  return (ushort)u;
}
__device__ __forceinline__ float sigmoid_f(float x){ return 1.f/(1.f + expf(-x)); }

// ---------------- obs path ----------------

// one wave per (episode,step): ballot-based multi-hot -> sorted index extraction
__global__ __launch_bounds__(256) void k_idx(const float* __restrict__ obs, int* __restrict__ idx){
  const int n = blockIdx.x*4 + (threadIdx.x >> 6);
  const int lane = threadIdx.x & 63;
  float v0 = obs[(size_t)n*VOBS + lane];
  float v1 = obs[(size_t)n*VOBS + 64 + lane];
  unsigned long long m0 = __ballot(v0 > 0.5f);
  unsigned long long m1 = __ballot(v1 > 0.5f);
  unsigned long long lt = (1ull << lane) - 1ull;
  if (v0 > 0.5f){
    int pos = __popcll(m0 & lt);
    if (pos < KOBS) idx[n*KOBS + pos] = lane;
  }
  if (v1 > 0.5f){
    int pos = __popcll(m0) + __popcll(m1 & lt);
    if (pos < KOBS) idx[n*KOBS + pos] = 64 + lane;
  }
}

// contrib[v][k][h] = sum_j prelu(obs_emb[v][j]) * obs_W[(k*H+j)*H + h]
__global__ __launch_bounds__(256) void k_contrib(
    const float* __restrict__ obs_emb, const float* __restrict__ a_emb_p,
    const float* __restrict__ obs_W, float* __restrict__ contrib){
  const int k = blockIdx.x;          // 0..31
  const int vbase = blockIdx.y*16;   // 0,16,...,112
  const int tid = threadIdx.x;       // h
  __shared__ float pe[16][H_];
  float a = a_emb_p[0];
  for (int i = tid; i < 16*H_; i += 256){
    int v = i >> 8, j = i & 255;
    pe[v][j] = prelu_f(obs_emb[(size_t)(vbase+v)*H_ + j], a);
  }
  __syncthreads();
  float acc[16];
  #pragma unroll
  for (int v = 0; v < 16; ++v) acc[v] = 0.f;
  for (int j = 0; j < H_; ++j){
    float w = obs_W[((size_t)(k*H_ + j))*H_ + tid];
    #pragma unroll
    for (int v = 0; v < 16; ++v) acc[v] += pe[v][j]*w;
  }
  for (int v = 0; v < 16; ++v)
    contrib[((size_t)((vbase+v)*KOBS + k))*H_ + tid] = acc[v];
}

__global__ __launch_bounds__(256) void k_obs_o(
    const int* __restrict__ idx, const float* __restrict__ contrib,
    const float* __restrict__ obs_b, const float* __restrict__ obs_a_p,
    float* __restrict__ out){
  const int n = blockIdx.x, tid = threadIdx.x;
  __shared__ int id[KOBS];
  if (tid < KOBS) id[tid] = idx[n*KOBS + tid];
  __syncthreads();
  float acc = obs_b[tid];
  #pragma unroll 8
  for (int k = 0; k < KOBS; ++k)
    acc += contrib[((size_t)(id[k]*KOBS + k))*H_ + tid];
  out[(size_t)n*512 + tid] = prelu_f(acc, obs_a_p[0]);
}

// ---------------- comm path ----------------

__global__ void k_tok(const float* __restrict__ comm, int* __restrict__ tok){
  int i = blockIdx.x*blockDim.x + threadIdx.x; // (n,l) flat
  if (i >= N_*L_) return;
  const float4* p = (const float4*)(comm + (size_t)i*VCOMM);
  float best = -1e30f; int bi = 0;
  #pragma unroll
  for (int j = 0; j < 8; ++j){
    float4 q = p[j];
    if (q.x > best){ best = q.x; bi = j*4+0; }
    if (q.y > best){ best = q.y; bi = j*4+1; }
    if (q.z > best){ best = q.z; bi = j*4+2; }
    if (q.w > best){ best = q.w; bi = j*4+3; }
  }
  tok[i] = bi;
}

// P[slot][v][c] = sum_h prelu(comm_emb[v][h]) * w_g[c][h][tap]
__global__ void k_P(const float* __restrict__ comm_emb, const float* __restrict__ ca_p,
                    const float* __restrict__ cw1, const float* __restrict__ cw3,
                    const float* __restrict__ cw5, const float* __restrict__ cw7,
                    float* __restrict__ P){
  const int slot = blockIdx.x, v = blockIdx.y, c = threadIdx.x;
  int g, tap;
  if (slot == 0){ g=0; tap=0; }
  else if (slot < 4){ g=1; tap=slot-1; }
  else if (slot < 9){ g=2; tap=slot-4; }
  else { g=3; tap=slot-9; }
  const float* w; int ks;
  if (g==0){ w=cw1; ks=1; } else if (g==1){ w=cw3; ks=3; }
  else if (g==2){ w=cw5; ks=5; } else { w=cw7; ks=7; }
  float a = ca_p[0];
  float acc = 0.f;
  for (int h = 0; h < H_; ++h){
    float e = prelu_f(comm_emb[(size_t)v*H_ + h], a);
    acc += e * w[(size_t)(c*H_ + h)*ks + tap];
  }
  P[(size_t)(slot*VCOMM + v)*64 + c] = acc;
}

// Fully-unrolled conv gather: KS compile-time -> bounds checks fold away,
// one ds_read + one add per tap. Per wave: 4 n-rows, token bases in regs.
template<int KS, bool APPLY>
__device__ __forceinline__ void conv_work(
    const float* __restrict__ Ps, const int tk[16][L_], int wave, int lane,
    float bias, float scale, float shift, float ca,
    ushort* __restrict__ ynorm, int nbase, int g,
    float* s_out, float* q_out)
{
  constexpr int PAD = (KS-1)/2;
  float s = 0.f, sq = 0.f;
  for (int j = 0; j < 4; ++j){
    const int nn = wave*4 + j;
    int base[L_];
    #pragma unroll
    for (int l = 0; l < L_; ++l) base[l] = tk[nn][l]*64 + lane;
    #pragma unroll
    for (int l = 0; l < L_; ++l){
      float acc = bias;
      #pragma unroll
      for (int t = 0; t < KS; ++t){
        const int lp = l + t - PAD;
        if (lp >= 0 && lp < L_) acc += Ps[t*2048 + base[lp]];
      }
      if (APPLY){
        float y = prelu_f(fmaf(acc, scale, shift), ca);
        ynorm[((size_t)l*N_ + (nbase+nn))*H_ + g*64 + lane] = f2bf(y);
      } else {
        s += acc; sq += acc*acc;
      }
    }
  }
  *s_out = s; *q_out = sq;
}

__global__ __launch_bounds__(256) void k_conv_stats(
    const int* __restrict__ tok, const float* __restrict__ P,
    const float* __restrict__ cb1, const float* __restrict__ cb3,
    const float* __restrict__ cb5, const float* __restrict__ cb7,
    float* __restrict__ stats){
  const int g = blockIdx.y;
  const int nbase = blockIdx.x*16;
  const int tid = threadIdx.x, lane = tid & 63, wave = tid >> 6;
  const int ks = 2*g + 1, base = g*g;
  const float* cb = (g==0)?cb1:(g==1)?cb3:(g==2)?cb5:cb7;
  const float bias = cb[lane];
  __shared__ float Ps[7*2048];
  __shared__ int tk[16][L_];
  __shared__ float red_s[4][64], red_q[4][64];
  for (int i = tid; i < ks*512; i += 256)
    ((float4*)Ps)[i] = ((const float4*)(P + base*2048))[i];
  for (int i = tid; i < 16*L_; i += 256)
    tk[i>>5][i&31] = tok[(size_t)(nbase + (i>>5))*L_ + (i&31)];
  __syncthreads();
  float s = 0.f, sq = 0.f;
  switch (g){
    case 0: conv_work<1,false>(Ps, tk, wave, lane, bias, 0,0,0, nullptr, nbase, g, &s, &sq); break;
    case 1: conv_work<3,false>(Ps, tk, wave, lane, bias, 0,0,0, nullptr, nbase, g, &s, &sq); break;
    case 2: conv_work<5,false>(Ps, tk, wave, lane, bias, 0,0,0, nullptr, nbase, g, &s, &sq); break;
    default: conv_work<7,false>(Ps, tk, wave, lane, bias, 0,0,0, nullptr, nbase, g, &s, &sq); break;
  }
  red_s[wave][lane] = s; red_q[wave][lane] = sq;
  __syncthreads();
  if (wave == 0){
    float ts = red_s[0][lane]+red_s[1][lane]+red_s[2][lane]+red_s[3][lane];
    float tq = red_q[0][lane]+red_q[1][lane]+red_q[2][lane]+red_q[3][lane];
    atomicAdd(&stats[g*64 + lane], ts);
    atomicAdd(&stats[256 + g*64 + lane], tq);
  }
}

__global__ void k_bn_fin(const float* __restrict__ stats, const float* __restrict__ bn_g,
                         const float* __restrict__ bn_b, float* __restrict__ ss){
  int t = threadIdx.x;
  const float cnt = (float)(N_*L_);
  float m = stats[t]/cnt;
  float v = stats[256+t]/cnt - m*m;
  float sc = bn_g[t] / sqrtf(v + 1e-5f);
  ss[t] = sc; ss[256+t] = bn_b[t] - m*sc;
}

__global__ __launch_bounds__(256) void k_conv_apply(
    const int* __restrict__ tok, const float* __restrict__ P,
    const float* __restrict__ cb1, const float* __restrict__ cb3,
    const float* __restrict__ cb5, const float* __restrict__ cb7,
    const float* __restrict__ ss, const float* __restrict__ cnn_a_p,
    ushort* __restrict__ ynorm){
  const int g = blockIdx.y;
  const int nbase = blockIdx.x*16;
  const int tid = threadIdx.x, lane = tid & 63, wave = tid >> 6;
  const int ks = 2*g + 1, base = g*g;
  const float* cb = (g==0)?cb1:(g==1)?cb3:(g==2)?cb5:cb7;
  const float bias = cb[lane];
  const float scale = ss[g*64 + lane], shift = ss[256 + g*64 + lane];
  const float ca = cnn_a_p[0];
  __shared__ float Ps[7*2048];
  __shared__ int tk[16][L_];
  for (int i = tid; i < ks*512; i += 256)
    ((float4*)Ps)[i] = ((const float4*)(P + base*2048))[i];
  for (int i = tid; i < 16*L_; i += 256)
    tk[i>>5][i&31] = tok[(size_t)(nbase + (i>>5))*L_ + (i&31)];
  __syncthreads();
  float s, q;
  switch (g){
    case 0: conv_work<1,true>(Ps, tk, wave, lane, bias, scale, shift, ca, ynorm, nbase, g, &s, &q); break;
    case 1: conv_work<3,true>(Ps, tk, wave, lane, bias, scale, shift, ca, ynorm, nbase, g, &s, &q); break;
    case 2: conv_work<5,true>(Ps, tk, wave, lane, bias, scale, shift, ca, ynorm, nbase, g, &s, &q); break;
    default: conv_work<7,true>(Ps, tk, wave, lane, bias, scale, shift, ca, ynorm, nbase, g, &s, &q); break;
  }
}

// ---------------- GRU scan ----------------

// WT2[row=u*4+g][k], k in [0,512). g: 0=r, 1=z, 2=x-part of n, 3=h-part of n
__global__ void k_WT2(const float* __restrict__ Wx, const float* __restrict__ Wh,
                      ushort* __restrict__ WT2){
  int id = blockIdx.x*blockDim.x + threadIdx.x;  // 0..524287
  int row = id >> 9, k = id & 511;
  int u = row >> 2, g = row & 3;
  float val = 0.f;
  if (g == 0)      val = (k<256) ? Wx[(size_t)k*256 + u]        : Wh[(size_t)(k-256)*256 + u];
  else if (g == 1) val = (k<256) ? Wx[(size_t)(256+k)*256 + u]  : Wh[(size_t)(256+(k-256))*256 + u];
  else if (g == 2) val = (k<256) ? Wx[(size_t)(512+k)*256 + u]  : 0.f;
  else             val = (k<256) ? 0.f : Wh[(size_t)(512+(k-256))*256 + u];
  WT2[id] = f2bf(val);
}

// Fused step: C = [ynorm_l | hbf_in] x WT2^T, gate epilogue, writes h_out/hbf_out.
// BM=64, BN=256 (one 64-u slice, all 4 gates). grid (64,4) = 256 blocks.
__global__ __launch_bounds__(256) void k_step_fused(
    const ushort* __restrict__ Ay, const ushort* __restrict__ hbf_in,
    const float* __restrict__ h_in, const ushort* __restrict__ WT2,
    const float* __restrict__ bx, const float* __restrict__ bh,
    float* __restrict__ h_out, ushort* __restrict__ hbf_out)
{
  const int bm = blockIdx.x, bn = blockIdx.y;
  const int tid = threadIdx.x;
  const int lane = tid & 63;
  const int w = tid >> 6;            // wave id: cols [w*64, w*64+64)
  const int quad = lane >> 4, l16 = lane & 15;

  __shared__ __align__(16) ushort As[64][40];
  __shared__ __align__(16) ushort Bs[256][40];
  __shared__ float Ep[16*266];

  floatx4 acc[4][4];
  #pragma unroll
  for (int i = 0; i < 4; ++i)
    #pragma unroll
    for (int j = 0; j < 4; ++j)
      acc[i][j] = (floatx4){0.f,0.f,0.f,0.f};

  const ushort* Abase = Ay + (size_t)bm*64*H_;
  const ushort* Hbase = hbf_in + (size_t)bm*64*H_;
  const ushort* Bbase = WT2 + (size_t)bn*256*512;

  for (int kt = 0; kt < 16; ++kt){
    __syncthreads();
    // A tile: 64 rows x 32 k -> 256 chunks of 8 ushorts (1/thread)
    {
      int row = tid >> 2, kc = tid & 3;
      const ushort* src = (kt < 8)
        ? Abase + (size_t)row*H_ + kt*32 + kc*8
        : Hbase + (size_t)row*H_ + (kt-8)*32 + kc*8;
      *(uint4*)&As[row][kc*8] = *(const uint4*)src;
    }
    // B tile: 256 rows x 32 k -> 1024 chunks (4/thread)
    #pragma unroll
    for (int i = 0; i < 4; ++i){
      int chunk = i*256 + tid;
      int row = chunk >> 2, kc = chunk & 3;
      *(uint4*)&Bs[row][kc*8] = *(const uint4*)(Bbase + (size_t)row*512 + kt*32 + kc*8);
    }
    __syncthreads();
    short8 a[4], b[4];
    #pragma unroll
    for (int mi = 0; mi < 4; ++mi)
      a[mi] = *(const short8*)&As[mi*16 + l16][quad*8];
    #pragma unroll
    for (int ni = 0; ni < 4; ++ni)
      b[ni] = *(const short8*)&Bs[w*64 + ni*16 + l16][quad*8];
    #pragma unroll
    for (int mi = 0; mi < 4; ++mi)
      #pragma unroll
      for (int ni = 0; ni < 4; ++ni)
        acc[mi][ni] = __builtin_amdgcn_mfma_f32_16x16x32_bf16(a[mi], b[ni], acc[mi][ni], 0,0,0);
  }

  // Epilogue: per 16-row round, de-interleave gates through LDS, compute GRU cell.
  for (int mi = 0; mi < 4; ++mi){
    __syncthreads();
    #pragma unroll
    for (int ni = 0; ni < 4; ++ni){
      int c = w*64 + ni*16 + l16;
      int u = c >> 2, g = c & 3;
      #pragma unroll
      for (int r = 0; r < 4; ++r)
        Ep[(quad*4 + r)*266 + g*66 + u] = acc[mi][ni][r];
    }
    __syncthreads();
    int u = tid & 63;
    int uu = bn*64 + u;
    float b0 = bx[uu] + bh[uu];
    float b1 = bx[256+uu] + bh[256+uu];
    float b2x = bx[512+uu], b2h = bh[512+uu];
    #pragma unroll
    for (int rr = 0; rr < 4; ++rr){
      int r = (tid >> 6) + rr*4;
      float o0 = Ep[r*266 + u];
      float o1 = Ep[r*266 + 66 + u];
      float o2 = Ep[r*266 + 132 + u];
      float o3 = Ep[r*266 + 198 + u];
      int row_g = bm*64 + mi*16 + r;
      float rg = sigmoid_f(o0 + b0);
      float zg = sigmoid_f(o1 + b1);
      float ng = tanhf(o2 + b2x + rg*(o3 + b2h));
      float hold = h_in[(size_t)row_g*H_ + uu];
      float hv = ng*(1.f - zg) + hold*zg;
      h_out[(size_t)row_g*H_ + uu] = hv;
      hbf_out[(size_t)row_g*H_ + uu] = f2bf(hv);
    }
  }
}

// c = prelu(prelu(h,a1) @ lin_W + lin_b, a2) -> out[..., 256:512]
__global__ __launch_bounds__(256) void k_final(
    const float* __restrict__ h, const float* __restrict__ a1p,
    const float* __restrict__ lin_W, const float* __restrict__ lin_b,
    const float* __restrict__ a2p, float* __restrict__ out){
  const int nbase = blockIdx.x*16, tid = threadIdx.x;
  __shared__ float hp[16][H_];
  const float a1 = a1p[0], a2 = a2p[0];
  for (int i = tid; i < 16*H_; i += 256)
    hp[i>>8][i&255] = prelu_f(h[(size_t)(nbase + (i>>8))*H_ + (i&255)], a1);
  __syncthreads();
  float acc[16];
  const float b = lin_b[tid];
  #pragma unroll
  for (int r = 0; r < 16; ++r) acc[r] = b;
  for (int j = 0; j < H_; ++j){
    float w = lin_W[(size_t)j*H_ + tid];
    #pragma unroll
    for (int r = 0; r < 16; ++r) acc[r] += hp[r][j]*w;
  }
  for (int r = 0; r < 16; ++r)
    out[(size_t)(nbase+r)*512 + 256 + tid] = prelu_f(acc[r], a2);
}

extern "C" void kernel_launch(void* const* d_in, const int* in_sizes, int n_in,
                              void* d_out, int out_size, void* d_ws, size_t ws_size,
                              hipStream_t stream) {
  (void)in_sizes; (void)n_in; (void)out_size; (void)ws_size;
  const float* obs      = (const float*)d_in[0];
  const float* comm     = (const float*)d_in[1];
  const float* obs_emb  = (const float*)d_in[2];
  const float* obs_a_emb= (const float*)d_in[3];
  const float* obs_W    = (const float*)d_in[4];
  const float* obs_b    = (const float*)d_in[5];
  const float* obs_a    = (const float*)d_in[6];
  const float* comm_emb = (const float*)d_in[7];
  const float* comm_a   = (const float*)d_in[8];
  const float* cw1      = (const float*)d_in[9];
  const float* cb1      = (const float*)d_in[10];
  const float* cw3      = (const float*)d_in[11];
  const float* cb3      = (const float*)d_in[12];
  const float* cw5      = (const float*)d_in[13];
  const float* cb5      = (const float*)d_in[14];
  const float* cw7      = (const float*)d_in[15];
  const float* cb7      = (const float*)d_in[16];
  const float* bn_g     = (const float*)d_in[17];
  const float* bn_b     = (const float*)d_in[18];
  const float* cnn_a    = (const float*)d_in[19];
  const float* Wx       = (const float*)d_in[20];
  const float* bx       = (const float*)d_in[21];
  const float* Wh       = (const float*)d_in[22];
  const float* bh       = (const float*)d_in[23];
  const float* lin_a1   = (const float*)d_in[24];
  const float* lin_W    = (const float*)d_in[25];
  const float* lin_b    = (const float*)d_in[26];
  const float* lin_a2   = (const float*)d_in[27];
  float* out = (float*)d_out;

  char* ws = (char*)d_ws;
  float*  contrib = (float*)(ws + 0);            // 4,194,304
  float*  P       = (float*)(ws + 4194304);      // 131,072
  int*    idx     = (int*)  (ws + 4325376);      // 524,288
  int*    tok     = (int*)  (ws + 4849664);      // 524,288
  float*  stats   = (float*)(ws + 5373952);      // 2,048
  float*  ss      = (float*)(ws + 5376000);      // 2,048
  ushort* WT2     = (ushort*)(ws + 5378048);     // 1,048,576
  float*  h_a     = (float*)(ws + 6426624);      // 4,194,304
  float*  h_b     = (float*)(ws + 10620928);     // 4,194,304
  ushort* hbf_a   = (ushort*)(ws + 14815232);    // 2,097,152
  ushort* hbf_b   = (ushort*)(ws + 16912384);    // 2,097,152
  ushort* ynorm   = (ushort*)(ws + 19009536);    // 67,108,864

  hipMemsetAsync(stats, 0, 512*sizeof(float), stream);
  hipMemsetAsync(h_a, 0, (size_t)N_*H_*sizeof(float), stream);
  hipMemsetAsync(hbf_a, 0, (size_t)N_*H_*sizeof(ushort), stream);

  k_idx<<<1024, 256, 0, stream>>>(obs, idx);
  k_tok<<<512, 256, 0, stream>>>(comm, tok);
  k_WT2<<<2048, 256, 0, stream>>>(Wx, Wh, WT2);
  k_P<<<dim3(16,32), 64, 0, stream>>>(comm_emb, comm_a, cw1, cw3, cw5, cw7, P);
  k_contrib<<<dim3(32,8), 256, 0, stream>>>(obs_emb, obs_a_emb, obs_W, contrib);
  k_obs_o<<<4096, 256, 0, stream>>>(idx, contrib, obs_b, obs_a, out);
  k_conv_stats<<<dim3(256,4), 256, 0, stream>>>(tok, P, cb1, cb3, cb5, cb7, stats);
  k_bn_fin<<<1, 256, 0, stream>>>(stats, bn_g, bn_b, ss);
  k_conv_apply<<<dim3(256,4), 256, 0, stream>>>(tok, P, cb1, cb3, cb5, cb7, ss, cnn_a, ynorm);

  for (int l = 0; l < L_; ++l){
    const float*  hi  = (l & 1) ? h_b   : h_a;
    const ushort* hbi = (l & 1) ? hbf_b : hbf_a;
    float*  ho  = (l & 1) ? h_a   : h_b;
    ushort* hbo = (l & 1) ? hbf_a : hbf_b;
    k_step_fused<<<dim3(64,4), 256, 0, stream>>>(
        ynorm + (size_t)l*N_*H_, hbi, hi, WT2, bx, bh, ho, hbo);
  }
  // 32 steps: last (l=31, odd) wrote h_a
  k_final<<<256, 256, 0, stream>>>(h_a, lin_a1, lin_W, lin_b, lin_a2, out);
}

// Round 4
// 803.060 us; speedup vs baseline: 2.6516x; 1.1010x over previous
//
#include <hip/hip_runtime.h>
#include <hip/hip_bf16.h>

#define E_ 64
#define S_ 64
#define N_ 4096      // E*S
#define VOBS 128
#define KOBS 32
#define H_ 256
#define L_ 32
#define VCOMM 32

typedef __attribute__((ext_vector_type(8))) short short8;
typedef __attribute__((ext_vector_type(4))) float floatx4;

__device__ __forceinline__ float prelu_f(float x, float a){ return x >= 0.f ? x : a*x; }
__device__ __forceinline__ ushort f2bf(float x){
  unsigned int u = __float_as_uint(x);
  u = (u + 0x7FFFu + ((u >> 16) & 1u)) >> 16;
  return (ushort)u;
}
__device__ __forceinline__ float bf2f(ushort x){
  unsigned int u = ((unsigned int)x) << 16;
  return __uint_as_float(u);
}
__device__ __forceinline__ float sigmoid_f(float x){ return 1.f/(1.f + expf(-x)); }

// ---------------- obs path ----------------

__global__ __launch_bounds__(256) void k_idx(const float* __restrict__ obs, int* __restrict__ idx){
  const int n = blockIdx.x*4 + (threadIdx.x >> 6);
  const int lane = threadIdx.x & 63;
  float v0 = obs[(size_t)n*VOBS + lane];
  float v1 = obs[(size_t)n*VOBS + 64 + lane];
  unsigned long long m0 = __ballot(v0 > 0.5f);
  unsigned long long m1 = __ballot(v1 > 0.5f);
  unsigned long long lt = (1ull << lane) - 1ull;
  if (v0 > 0.5f){
    int pos = __popcll(m0 & lt);
    if (pos < KOBS) idx[n*KOBS + pos] = lane;
  }
  if (v1 > 0.5f){
    int pos = __popcll(m0) + __popcll(m1 & lt);
    if (pos < KOBS) idx[n*KOBS + pos] = 64 + lane;
  }
}

// contrib[v][k][h] = sum_j prelu(obs_emb[v][j]) * obs_W[(k*H+j)*H + h]
__global__ __launch_bounds__(256) void k_contrib(
    const float* __restrict__ obs_emb, const float* __restrict__ a_emb_p,
    const float* __restrict__ obs_W, float* __restrict__ contrib){
  const int k = blockIdx.x;          // 0..31
  const int vbase = blockIdx.y*16;   // 0,16,...,112
  const int tid = threadIdx.x;       // h
  __shared__ float pe[16][H_];
  float a = a_emb_p[0];
  for (int i = tid; i < 16*H_; i += 256){
    int v = i >> 8, j = i & 255;
    pe[v][j] = prelu_f(obs_emb[(size_t)(vbase+v)*H_ + j], a);
  }
  __syncthreads();
  float acc[16];
  #pragma unroll
  for (int v = 0; v < 16; ++v) acc[v] = 0.f;
  for (int j = 0; j < H_; ++j){
    float w = obs_W[((size_t)(k*H_ + j))*H_ + tid];
    #pragma unroll
    for (int v = 0; v < 16; ++v) acc[v] += pe[v][j]*w;
  }
  for (int v = 0; v < 16; ++v)
    contrib[((size_t)((vbase+v)*KOBS + k))*H_ + tid] = acc[v];
}

__global__ __launch_bounds__(256) void k_obs_o(
    const int* __restrict__ idx, const float* __restrict__ contrib,
    const float* __restrict__ obs_b, const float* __restrict__ obs_a_p,
    float* __restrict__ out){
  const int n = blockIdx.x, tid = threadIdx.x;
  __shared__ int id[KOBS];
  if (tid < KOBS) id[tid] = idx[n*KOBS + tid];
  __syncthreads();
  float acc = obs_b[tid];
  #pragma unroll 8
  for (int k = 0; k < KOBS; ++k)
    acc += contrib[((size_t)(id[k]*KOBS + k))*H_ + tid];
  out[(size_t)n*512 + tid] = prelu_f(acc, obs_a_p[0]);
}

// ---------------- comm path ----------------

__global__ void k_tok(const float* __restrict__ comm, int* __restrict__ tok){
  int i = blockIdx.x*blockDim.x + threadIdx.x; // (n,l) flat
  if (i >= N_*L_) return;
  const float4* p = (const float4*)(comm + (size_t)i*VCOMM);
  float best = -1e30f; int bi = 0;
  #pragma unroll
  for (int j = 0; j < 8; ++j){
    float4 q = p[j];
    if (q.x > best){ best = q.x; bi = j*4+0; }
    if (q.y > best){ best = q.y; bi = j*4+1; }
    if (q.z > best){ best = q.z; bi = j*4+2; }
    if (q.w > best){ best = q.w; bi = j*4+3; }
  }
  tok[i] = bi;
}

// P[slot][v][c] = sum_h prelu(comm_emb[v][h]) * w_g[c][h][tap]
__global__ void k_P(const float* __restrict__ comm_emb, const float* __restrict__ ca_p,
                    const float* __restrict__ cw1, const float* __restrict__ cw3,
                    const float* __restrict__ cw5, const float* __restrict__ cw7,
                    float* __restrict__ P){
  const int slot = blockIdx.x, v = blockIdx.y, c = threadIdx.x;
  int g, tap;
  if (slot == 0){ g=0; tap=0; }
  else if (slot < 4){ g=1; tap=slot-1; }
  else if (slot < 9){ g=2; tap=slot-4; }
  else { g=3; tap=slot-9; }
  const float* w; int ks;
  if (g==0){ w=cw1; ks=1; } else if (g==1){ w=cw3; ks=3; }
  else if (g==2){ w=cw5; ks=5; } else { w=cw7; ks=7; }
  float a = ca_p[0];
  float acc = 0.f;
  for (int h = 0; h < H_; ++h){
    float e = prelu_f(comm_emb[(size_t)v*H_ + h], a);
    acc += e * w[(size_t)(c*H_ + h)*ks + tap];
  }
  P[(size_t)(slot*VCOMM + v)*64 + c] = acc;
}

template<int KS, bool APPLY>
__device__ __forceinline__ void conv_work(
    const float* __restrict__ Ps, const int tk[16][L_], int wave, int lane,
    float bias, float scale, float shift, float ca,
    ushort* __restrict__ ynorm, int nbase, int g,
    float* s_out, float* q_out)
{
  constexpr int PAD = (KS-1)/2;
  float s = 0.f, sq = 0.f;
  for (int j = 0; j < 4; ++j){
    const int nn = wave*4 + j;
    int base[L_];
    #pragma unroll
    for (int l = 0; l < L_; ++l) base[l] = tk[nn][l]*64 + lane;
    #pragma unroll
    for (int l = 0; l < L_; ++l){
      float acc = bias;
      #pragma unroll
      for (int t = 0; t < KS; ++t){
        const int lp = l + t - PAD;
        if (lp >= 0 && lp < L_) acc += Ps[t*2048 + base[lp]];
      }
      if (APPLY){
        float y = prelu_f(fmaf(acc, scale, shift), ca);
        ynorm[((size_t)l*N_ + (nbase+nn))*H_ + g*64 + lane] = f2bf(y);
      } else {
        s += acc; sq += acc*acc;
      }
    }
  }
  *s_out = s; *q_out = sq;
}

__global__ __launch_bounds__(256) void k_conv_stats(
    const int* __restrict__ tok, const float* __restrict__ P,
    const float* __restrict__ cb1, const float* __restrict__ cb3,
    const float* __restrict__ cb5, const float* __restrict__ cb7,
    float* __restrict__ stats){
  const int g = blockIdx.y;
  const int nbase = blockIdx.x*16;
  const int tid = threadIdx.x, lane = tid & 63, wave = tid >> 6;
  const int ks = 2*g + 1, base = g*g;
  const float* cb = (g==0)?cb1:(g==1)?cb3:(g==2)?cb5:cb7;
  const float bias = cb[lane];
  __shared__ float Ps[7*2048];
  __shared__ int tk[16][L_];
  __shared__ float red_s[4][64], red_q[4][64];
  for (int i = tid; i < ks*512; i += 256)
    ((float4*)Ps)[i] = ((const float4*)(P + base*2048))[i];
  for (int i = tid; i < 16*L_; i += 256)
    tk[i>>5][i&31] = tok[(size_t)(nbase + (i>>5))*L_ + (i&31)];
  __syncthreads();
  float s = 0.f, sq = 0.f;
  switch (g){
    case 0: conv_work<1,false>(Ps, tk, wave, lane, bias, 0,0,0, nullptr, nbase, g, &s, &sq); break;
    case 1: conv_work<3,false>(Ps, tk, wave, lane, bias, 0,0,0, nullptr, nbase, g, &s, &sq); break;
    case 2: conv_work<5,false>(Ps, tk, wave, lane, bias, 0,0,0, nullptr, nbase, g, &s, &sq); break;
    default: conv_work<7,false>(Ps, tk, wave, lane, bias, 0,0,0, nullptr, nbase, g, &s, &sq); break;
  }
  red_s[wave][lane] = s; red_q[wave][lane] = sq;
  __syncthreads();
  if (wave == 0){
    float ts = red_s[0][lane]+red_s[1][lane]+red_s[2][lane]+red_s[3][lane];
    float tq = red_q[0][lane]+red_q[1][lane]+red_q[2][lane]+red_q[3][lane];
    atomicAdd(&stats[g*64 + lane], ts);
    atomicAdd(&stats[256 + g*64 + lane], tq);
  }
}

__global__ void k_bn_fin(const float* __restrict__ stats, const float* __restrict__ bn_g,
                         const float* __restrict__ bn_b, float* __restrict__ ss){
  int t = threadIdx.x;
  const float cnt = (float)(N_*L_);
  float m = stats[t]/cnt;
  float v = stats[256+t]/cnt - m*m;
  float sc = bn_g[t] / sqrtf(v + 1e-5f);
  ss[t] = sc; ss[256+t] = bn_b[t] - m*sc;
}

__global__ __launch_bounds__(256) void k_conv_apply(
    const int* __restrict__ tok, const float* __restrict__ P,
    const float* __restrict__ cb1, const float* __restrict__ cb3,
    const float* __restrict__ cb5, const float* __restrict__ cb7,
    const float* __restrict__ ss, const float* __restrict__ cnn_a_p,
    ushort* __restrict__ ynorm){
  const int g = blockIdx.y;
  const int nbase = blockIdx.x*16;
  const int tid = threadIdx.x, lane = tid & 63, wave = tid >> 6;
  const int ks = 2*g + 1, base = g*g;
  const float* cb = (g==0)?cb1:(g==1)?cb3:(g==2)?cb5:cb7;
  const float bias = cb[lane];
  const float scale = ss[g*64 + lane], shift = ss[256 + g*64 + lane];
  const float ca = cnn_a_p[0];
  __shared__ float Ps[7*2048];
  __shared__ int tk[16][L_];
  for (int i = tid; i < ks*512; i += 256)
    ((float4*)Ps)[i] = ((const float4*)(P + base*2048))[i];
  for (int i = tid; i < 16*L_; i += 256)
    tk[i>>5][i&31] = tok[(size_t)(nbase + (i>>5))*L_ + (i&31)];
  __syncthreads();
  float s, q;
  switch (g){
    case 0: conv_work<1,true>(Ps, tk, wave, lane, bias, scale, shift, ca, ynorm, nbase, g, &s, &q); break;
    case 1: conv_work<3,true>(Ps, tk, wave, lane, bias, scale, shift, ca, ynorm, nbase, g, &s, &q); break;
    case 2: conv_work<5,true>(Ps, tk, wave, lane, bias, scale, shift, ca, ynorm, nbase, g, &s, &q); break;
    default: conv_work<7,true>(Ps, tk, wave, lane, bias, scale, shift, ca, ynorm, nbase, g, &s, &q); break;
  }
}

// ---------------- GRU scan ----------------

// Weight tables (bf16):
//   WhT3[c=u*3+g][k] = Wh[g][k][u]   (serial GEMM B; gate-fused epilogue locality)
//   WxT3[c=g*256+u][k] = Wx[g][k][u] (xproj GEMM B; coalesced xp reads)
__global__ void k_WT3(const float* __restrict__ Wx, const float* __restrict__ Wh,
                      ushort* __restrict__ WxT3, ushort* __restrict__ WhT3){
  int id = blockIdx.x*blockDim.x + threadIdx.x;  // 0..196607
  int g = id >> 16, k = (id >> 8) & 255, u = id & 255;
  float vx = Wx[(size_t)g*65536 + k*256 + u];
  float vh = Wh[(size_t)g*65536 + k*256 + u];
  WxT3[((size_t)(g*256 + u))*256 + k] = f2bf(vx);
  WhT3[((size_t)(u*3 + g))*256 + k] = f2bf(vh);
}

// xp[row][c] = Y[row][:] @ WxT3[c][:]  (row = l_local*4096 + n, c = g*256+u)
// BM=128, BN=128, BK=32, 8 kt. grid (512, 6).
__global__ __launch_bounds__(256) void k_xproj(
    const ushort* __restrict__ Y, const ushort* __restrict__ WxT3,
    ushort* __restrict__ xp)
{
  const int bm = blockIdx.x, bn = blockIdx.y;
  const int tid = threadIdx.x, lane = tid & 63, wave = tid >> 6;
  const int wm = wave >> 1, wn = wave & 1;
  const int quad = lane >> 4, l16 = lane & 15;
  __shared__ __align__(16) ushort As[128][40];
  __shared__ __align__(16) ushort Bs[128][40];
  floatx4 acc[4][4];
  #pragma unroll
  for (int i = 0; i < 4; ++i)
    #pragma unroll
    for (int j = 0; j < 4; ++j)
      acc[i][j] = (floatx4){0.f,0.f,0.f,0.f};
  const ushort* Abase = Y + (size_t)bm*128*H_;
  const ushort* Bbase = WxT3 + (size_t)bn*128*H_;
  for (int kt = 0; kt < 8; ++kt){
    __syncthreads();
    #pragma unroll
    for (int i = 0; i < 2; ++i){
      int chunk = i*256 + tid;
      int row = chunk >> 2, kc = chunk & 3;
      *(uint4*)&As[row][kc*8] = *(const uint4*)(Abase + (size_t)row*H_ + kt*32 + kc*8);
      *(uint4*)&Bs[row][kc*8] = *(const uint4*)(Bbase + (size_t)row*H_ + kt*32 + kc*8);
    }
    __syncthreads();
    short8 a[4], b[4];
    #pragma unroll
    for (int mi = 0; mi < 4; ++mi)
      a[mi] = *(const short8*)&As[wm*64 + mi*16 + l16][quad*8];
    #pragma unroll
    for (int ni = 0; ni < 4; ++ni)
      b[ni] = *(const short8*)&Bs[wn*64 + ni*16 + l16][quad*8];
    #pragma unroll
    for (int mi = 0; mi < 4; ++mi)
      #pragma unroll
      for (int ni = 0; ni < 4; ++ni)
        acc[mi][ni] = __builtin_amdgcn_mfma_f32_16x16x32_bf16(a[mi], b[ni], acc[mi][ni], 0,0,0);
  }
  #pragma unroll
  for (int mi = 0; mi < 4; ++mi)
    #pragma unroll
    for (int ni = 0; ni < 4; ++ni)
      #pragma unroll
      for (int r = 0; r < 4; ++r){
        int row = bm*128 + wm*64 + mi*16 + quad*4 + r;
        int col = bn*128 + wn*64 + ni*16 + l16;
        xp[(size_t)row*768 + col] = f2bf(acc[mi][ni][r]);
      }
}

// Serial step: C[64x96] = hbf_in[bm*64..][256] @ WhT3[bn*96..][256]^T + gate epilogue.
// BM=64, BN=96 (u-slice of 32, gates interleaved u*3+g). grid (64, 8) = 512 blocks.
__global__ __launch_bounds__(256) void k_step_h(
    const ushort* __restrict__ hbf_in, const float* __restrict__ h_in,
    const ushort* __restrict__ WhT3, const ushort* __restrict__ xp_l,
    const float* __restrict__ bx, const float* __restrict__ bh,
    float* __restrict__ h_out, ushort* __restrict__ hbf_out)
{
  const int bm = blockIdx.x, bn = blockIdx.y;
  const int tid = threadIdx.x, lane = tid & 63, wave = tid >> 6;
  const int wm = wave >> 1, wn = wave & 1;   // 2x2 waves, wave tile 32x48
  const int quad = lane >> 4, l16 = lane & 15;
  __shared__ __align__(16) ushort As[64][40];
  __shared__ __align__(16) ushort Bs[96][40];
  __shared__ float Ep[64][100];
  floatx4 acc[2][3];
  #pragma unroll
  for (int i = 0; i < 2; ++i)
    #pragma unroll
    for (int j = 0; j < 3; ++j)
      acc[i][j] = (floatx4){0.f,0.f,0.f,0.f};
  const ushort* Abase = hbf_in + (size_t)bm*64*H_;
  const ushort* Bbase = WhT3 + (size_t)bn*96*H_;
  for (int kt = 0; kt < 8; ++kt){
    __syncthreads();
    { // A: 64 rows x 32k -> 256 chunks
      int row = tid >> 2, kc = tid & 3;
      *(uint4*)&As[row][kc*8] = *(const uint4*)(Abase + (size_t)row*H_ + kt*32 + kc*8);
    }
    for (int i = tid; i < 384; i += 256){ // B: 96 rows x 32k -> 384 chunks
      int row = i >> 2, kc = i & 3;
      *(uint4*)&Bs[row][kc*8] = *(const uint4*)(Bbase + (size_t)row*H_ + kt*32 + kc*8);
    }
    __syncthreads();
    short8 a[2], b[3];
    #pragma unroll
    for (int mi = 0; mi < 2; ++mi)
      a[mi] = *(const short8*)&As[wm*32 + mi*16 + l16][quad*8];
    #pragma unroll
    for (int ni = 0; ni < 3; ++ni)
      b[ni] = *(const short8*)&Bs[wn*48 + ni*16 + l16][quad*8];
    #pragma unroll
    for (int mi = 0; mi < 2; ++mi)
      #pragma unroll
      for (int ni = 0; ni < 3; ++ni)
        acc[mi][ni] = __builtin_amdgcn_mfma_f32_16x16x32_bf16(a[mi], b[ni], acc[mi][ni], 0,0,0);
  }
  __syncthreads();
  #pragma unroll
  for (int mi = 0; mi < 2; ++mi)
    #pragma unroll
    for (int ni = 0; ni < 3; ++ni)
      #pragma unroll
      for (int r = 0; r < 4; ++r)
        Ep[wm*32 + mi*16 + quad*4 + r][wn*48 + ni*16 + l16] = acc[mi][ni][r];
  __syncthreads();
  // gate epilogue: thread -> u = tid&31, rows (tid>>5)*8 .. +8
  const int u = tid & 31;
  const int uu = bn*32 + u;
  const float b0 = bx[uu] + bh[uu];
  const float b1 = bx[256+uu] + bh[256+uu];
  const float b2x = bx[512+uu], b2h = bh[512+uu];
  #pragma unroll
  for (int rr = 0; rr < 8; ++rr){
    const int r = (tid >> 5)*8 + rr;
    const int n = bm*64 + r;
    float hr = Ep[r][u*3+0], hz = Ep[r][u*3+1], hn = Ep[r][u*3+2];
    const ushort* xq = xp_l + (size_t)n*768;
    float xr = bf2f(xq[uu]);
    float xz = bf2f(xq[256+uu]);
    float xn = bf2f(xq[512+uu]);
    float rg = sigmoid_f(xr + hr + b0);
    float zg = sigmoid_f(xz + hz + b1);
    float ng = tanhf(xn + b2x + rg*(hn + b2h));
    float hold = h_in[(size_t)n*H_ + uu];
    float hv = ng*(1.f - zg) + hold*zg;
    h_out[(size_t)n*H_ + uu] = hv;
    hbf_out[(size_t)n*H_ + uu] = f2bf(hv);
  }
}

// c = prelu(prelu(h,a1) @ lin_W + lin_b, a2) -> out[..., 256:512]
__global__ __launch_bounds__(256) void k_final(
    const float* __restrict__ h, const float* __restrict__ a1p,
    const float* __restrict__ lin_W, const float* __restrict__ lin_b,
    const float* __restrict__ a2p, float* __restrict__ out){
  const int nbase = blockIdx.x*16, tid = threadIdx.x;
  __shared__ float hp[16][H_];
  const float a1 = a1p[0], a2 = a2p[0];
  for (int i = tid; i < 16*H_; i += 256)
    hp[i>>8][i&255] = prelu_f(h[(size_t)(nbase + (i>>8))*H_ + (i&255)], a1);
  __syncthreads();
  float acc[16];
  const float b = lin_b[tid];
  #pragma unroll
  for (int r = 0; r < 16; ++r) acc[r] = b;
  for (int j = 0; j < H_; ++j){
    float w = lin_W[(size_t)j*H_ + tid];
    #pragma unroll
    for (int r = 0; r < 16; ++r) acc[r] += hp[r][j]*w;
  }
  for (int r = 0; r < 16; ++r)
    out[(size_t)(nbase+r)*512 + 256 + tid] = prelu_f(acc[r], a2);
}

extern "C" void kernel_launch(void* const* d_in, const int* in_sizes, int n_in,
                              void* d_out, int out_size, void* d_ws, size_t ws_size,
                              hipStream_t stream) {
  (void)in_sizes; (void)n_in; (void)out_size; (void)ws_size;
  const float* obs      = (const float*)d_in[0];
  const float* comm     = (const float*)d_in[1];
  const float* obs_emb  = (const float*)d_in[2];
  const float* obs_a_emb= (const float*)d_in[3];
  const float* obs_W    = (const float*)d_in[4];
  const float* obs_b    = (const float*)d_in[5];
  const float* obs_a    = (const float*)d_in[6];
  const float* comm_emb = (const float*)d_in[7];
  const float* comm_a   = (const float*)d_in[8];
  const float* cw1      = (const float*)d_in[9];
  const float* cb1      = (const float*)d_in[10];
  const float* cw3      = (const float*)d_in[11];
  const float* cb3      = (const float*)d_in[12];
  const float* cw5      = (const float*)d_in[13];
  const float* cb5      = (const float*)d_in[14];
  const float* cw7      = (const float*)d_in[15];
  const float* cb7      = (const float*)d_in[16];
  const float* bn_g     = (const float*)d_in[17];
  const float* bn_b     = (const float*)d_in[18];
  const float* cnn_a    = (const float*)d_in[19];
  const float* Wx       = (const float*)d_in[20];
  const float* bx       = (const float*)d_in[21];
  const float* Wh       = (const float*)d_in[22];
  const float* bh       = (const float*)d_in[23];
  const float* lin_a1   = (const float*)d_in[24];
  const float* lin_W    = (const float*)d_in[25];
  const float* lin_b    = (const float*)d_in[26];
  const float* lin_a2   = (const float*)d_in[27];
  float* out = (float*)d_out;

  char* ws = (char*)d_ws;
  float*  contrib = (float*)(ws + 0);            // 4,194,304
  float*  P       = (float*)(ws + 4194304);      // 131,072
  int*    idx     = (int*)  (ws + 4325376);      // 524,288
  int*    tok     = (int*)  (ws + 4849664);      // 524,288
  float*  stats   = (float*)(ws + 5373952);      // 2,048
  float*  ss      = (float*)(ws + 5376000);      // 2,048
  ushort* WxT3    = (ushort*)(ws + 5378048);     // 393,216
  ushort* WhT3    = (ushort*)(ws + 5771264);     // 393,216
  float*  h_a     = (float*)(ws + 6164480);      // 4,194,304
  float*  h_b     = (float*)(ws + 10358784);     // 4,194,304
  ushort* hbf_a   = (ushort*)(ws + 14553088);    // 2,097,152
  ushort* hbf_b   = (ushort*)(ws + 16650240);    // 2,097,152
  ushort* ynorm   = (ushort*)(ws + 18747392);    // 67,108,864
  ushort* xp      = (ushort*)(ws + 85856256);    // 100,663,296 (16 l's)

  hipMemsetAsync(stats, 0, 512*sizeof(float), stream);
  hipMemsetAsync(h_a, 0, (size_t)N_*H_*sizeof(float), stream);
  hipMemsetAsync(hbf_a, 0, (size_t)N_*H_*sizeof(ushort), stream);

  k_idx<<<1024, 256, 0, stream>>>(obs, idx);
  k_tok<<<512, 256, 0, stream>>>(comm, tok);
  k_WT3<<<768, 256, 0, stream>>>(Wx, Wh, WxT3, WhT3);
  k_P<<<dim3(16,32), 64, 0, stream>>>(comm_emb, comm_a, cw1, cw3, cw5, cw7, P);
  k_contrib<<<dim3(32,8), 256, 0, stream>>>(obs_emb, obs_a_emb, obs_W, contrib);
  k_obs_o<<<4096, 256, 0, stream>>>(idx, contrib, obs_b, obs_a, out);
  k_conv_stats<<<dim3(256,4), 256, 0, stream>>>(tok, P, cb1, cb3, cb5, cb7, stats);
  k_bn_fin<<<1, 256, 0, stream>>>(stats, bn_g, bn_b, ss);
  k_conv_apply<<<dim3(256,4), 256, 0, stream>>>(tok, P, cb1, cb3, cb5, cb7, ss, cnn_a, ynorm);

  for (int half = 0; half < 2; ++half){
    k_xproj<<<dim3(512,6), 256, 0, stream>>>(ynorm + (size_t)half*16*N_*H_, WxT3, xp);
    for (int l = half*16; l < half*16 + 16; ++l){
      const float*  hi  = (l & 1) ? h_b   : h_a;
      const ushort* hbi = (l & 1) ? hbf_b : hbf_a;
      float*  ho  = (l & 1) ? h_a   : h_b;
      ushort* hbo = (l & 1) ? hbf_a : hbf_b;
      k_step_h<<<dim3(64,8), 256, 0, stream>>>(
          hbi, hi, WhT3, xp + (size_t)(l & 15)*N_*768, bx, bh, ho, hbo);
    }
  }
  // 32 steps: last (l=31, odd) wrote h_a
  k_final<<<256, 256, 0, stream>>>(h_a, lin_a1, lin_W, lin_b, lin_a2, out);
}

// Round 5
// 785.596 us; speedup vs baseline: 2.7105x; 1.0222x over previous
//
#include <hip/hip_runtime.h>
#include <hip/hip_bf16.h>

#define N_ 4096      // E*S
#define VOBS 128
#define KOBS 32
#define H_ 256
#define L_ 32
#define VCOMM 32

typedef __attribute__((ext_vector_type(8))) short short8;
typedef __attribute__((ext_vector_type(4))) float floatx4;

__device__ __forceinline__ float prelu_f(float x, float a){ return x >= 0.f ? x : a*x; }
__device__ __forceinline__ ushort f2bf(float x){
  unsigned int u = __float_as_uint(x);
  u = (u + 0x7FFFu + ((u >> 16) & 1u)) >> 16;
  return (ushort)u;
}
__device__ __forceinline__ float bf2f(ushort x){
  unsigned int u = ((unsigned int)x) << 16;
  return __uint_as_float(u);
}
__device__ __forceinline__ float sigmoid_f(float x){ return 1.f/(1.f + expf(-x)); }

// async global->LDS 16B per lane; lds dest must be wave-uniform base (+lane*16 in HW)
__device__ __forceinline__ void gl_lds16(const ushort* __restrict__ src, ushort* dst){
  __builtin_amdgcn_global_load_lds(
      (const __attribute__((address_space(1))) unsigned int*)src,
      (__attribute__((address_space(3))) unsigned int*)dst, 16, 0, 0);
}

// stage 48KB (24576 ushorts) from g into lds; 12 wave-instructions per wave
__device__ __forceinline__ void stage48(const ushort* __restrict__ g, ushort* lds, int w, int lane){
  #pragma unroll
  for (int t = 0; t < 12; ++t){
    const int cb = (w*12 + t)*64;
    gl_lds16(g + (size_t)(cb + lane)*8, lds + (size_t)cb*8);
  }
}

// ---------------- obs path ----------------

__global__ __launch_bounds__(256) void k_idx(const float* __restrict__ obs, int* __restrict__ idx){
  const int n = blockIdx.x*4 + (threadIdx.x >> 6);
  const int lane = threadIdx.x & 63;
  float v0 = obs[(size_t)n*VOBS + lane];
  float v1 = obs[(size_t)n*VOBS + 64 + lane];
  unsigned long long m0 = __ballot(v0 > 0.5f);
  unsigned long long m1 = __ballot(v1 > 0.5f);
  unsigned long long lt = (1ull << lane) - 1ull;
  if (v0 > 0.5f){
    int pos = __popcll(m0 & lt);
    if (pos < KOBS) idx[n*KOBS + pos] = lane;
  }
  if (v1 > 0.5f){
    int pos = __popcll(m0) + __popcll(m1 & lt);
    if (pos < KOBS) idx[n*KOBS + pos] = 64 + lane;
  }
}

__global__ __launch_bounds__(256) void k_contrib(
    const float* __restrict__ obs_emb, const float* __restrict__ a_emb_p,
    const float* __restrict__ obs_W, float* __restrict__ contrib){
  const int k = blockIdx.x;
  const int vbase = blockIdx.y*16;
  const int tid = threadIdx.x;
  __shared__ float pe[16][H_];
  float a = a_emb_p[0];
  for (int i = tid; i < 16*H_; i += 256){
    int v = i >> 8, j = i & 255;
    pe[v][j] = prelu_f(obs_emb[(size_t)(vbase+v)*H_ + j], a);
  }
  __syncthreads();
  float acc[16];
  #pragma unroll
  for (int v = 0; v < 16; ++v) acc[v] = 0.f;
  for (int j = 0; j < H_; ++j){
    float w = obs_W[((size_t)(k*H_ + j))*H_ + tid];
    #pragma unroll
    for (int v = 0; v < 16; ++v) acc[v] += pe[v][j]*w;
  }
  for (int v = 0; v < 16; ++v)
    contrib[((size_t)((vbase+v)*KOBS + k))*H_ + tid] = acc[v];
}

__global__ __launch_bounds__(256) void k_obs_o(
    const int* __restrict__ idx, const float* __restrict__ contrib,
    const float* __restrict__ obs_b, const float* __restrict__ obs_a_p,
    float* __restrict__ out){
  const int n = blockIdx.x, tid = threadIdx.x;
  __shared__ int id[KOBS];
  if (tid < KOBS) id[tid] = idx[n*KOBS + tid];
  __syncthreads();
  float acc = obs_b[tid];
  #pragma unroll 8
  for (int k = 0; k < KOBS; ++k)
    acc += contrib[((size_t)(id[k]*KOBS + k))*H_ + tid];
  out[(size_t)n*512 + tid] = prelu_f(acc, obs_a_p[0]);
}

// ---------------- comm path ----------------

__global__ void k_tok(const float* __restrict__ comm, int* __restrict__ tok){
  int i = blockIdx.x*blockDim.x + threadIdx.x;
  if (i >= N_*L_) return;
  const float4* p = (const float4*)(comm + (size_t)i*VCOMM);
  float best = -1e30f; int bi = 0;
  #pragma unroll
  for (int j = 0; j < 8; ++j){
    float4 q = p[j];
    if (q.x > best){ best = q.x; bi = j*4+0; }
    if (q.y > best){ best = q.y; bi = j*4+1; }
    if (q.z > best){ best = q.z; bi = j*4+2; }
    if (q.w > best){ best = q.w; bi = j*4+3; }
  }
  tok[i] = bi;
}

__global__ void k_P(const float* __restrict__ comm_emb, const float* __restrict__ ca_p,
                    const float* __restrict__ cw1, const float* __restrict__ cw3,
                    const float* __restrict__ cw5, const float* __restrict__ cw7,
                    float* __restrict__ P){
  const int slot = blockIdx.x, v = blockIdx.y, c = threadIdx.x;
  int g, tap;
  if (slot == 0){ g=0; tap=0; }
  else if (slot < 4){ g=1; tap=slot-1; }
  else if (slot < 9){ g=2; tap=slot-4; }
  else { g=3; tap=slot-9; }
  const float* w; int ks;
  if (g==0){ w=cw1; ks=1; } else if (g==1){ w=cw3; ks=3; }
  else if (g==2){ w=cw5; ks=5; } else { w=cw7; ks=7; }
  float a = ca_p[0];
  float acc = 0.f;
  for (int h = 0; h < H_; ++h){
    float e = prelu_f(comm_emb[(size_t)v*H_ + h], a);
    acc += e * w[(size_t)(c*H_ + h)*ks + tap];
  }
  P[(size_t)(slot*VCOMM + v)*64 + c] = acc;
}

template<int KS, bool APPLY>
__device__ __forceinline__ void conv_work(
    const float* __restrict__ Ps, const int tk[16][L_], int wave, int lane,
    float bias, float scale, float shift, float ca,
    ushort* __restrict__ ynorm, int nbase, int g,
    float* s_out, float* q_out)
{
  constexpr int PAD = (KS-1)/2;
  float s = 0.f, sq = 0.f;
  for (int j = 0; j < 4; ++j){
    const int nn = wave*4 + j;
    int base[L_];
    #pragma unroll
    for (int l = 0; l < L_; ++l) base[l] = tk[nn][l]*64 + lane;
    #pragma unroll
    for (int l = 0; l < L_; ++l){
      float acc = bias;
      #pragma unroll
      for (int t = 0; t < KS; ++t){
        const int lp = l + t - PAD;
        if (lp >= 0 && lp < L_) acc += Ps[t*2048 + base[lp]];
      }
      if (APPLY){
        float y = prelu_f(fmaf(acc, scale, shift), ca);
        ynorm[((size_t)l*N_ + (nbase+nn))*H_ + g*64 + lane] = f2bf(y);
      } else {
        s += acc; sq += acc*acc;
      }
    }
  }
  *s_out = s; *q_out = sq;
}

__global__ __launch_bounds__(256) void k_conv_stats(
    const int* __restrict__ tok, const float* __restrict__ P,
    const float* __restrict__ cb1, const float* __restrict__ cb3,
    const float* __restrict__ cb5, const float* __restrict__ cb7,
    float* __restrict__ stats){
  const int g = blockIdx.y;
  const int nbase = blockIdx.x*16;
  const int tid = threadIdx.x, lane = tid & 63, wave = tid >> 6;
  const int ks = 2*g + 1, base = g*g;
  const float* cb = (g==0)?cb1:(g==1)?cb3:(g==2)?cb5:cb7;
  const float bias = cb[lane];
  __shared__ float Ps[7*2048];
  __shared__ int tk[16][L_];
  __shared__ float red_s[4][64], red_q[4][64];
  for (int i = tid; i < ks*512; i += 256)
    ((float4*)Ps)[i] = ((const float4*)(P + base*2048))[i];
  for (int i = tid; i < 16*L_; i += 256)
    tk[i>>5][i&31] = tok[(size_t)(nbase + (i>>5))*L_ + (i&31)];
  __syncthreads();
  float s = 0.f, sq = 0.f;
  switch (g){
    case 0: conv_work<1,false>(Ps, tk, wave, lane, bias, 0,0,0, nullptr, nbase, g, &s, &sq); break;
    case 1: conv_work<3,false>(Ps, tk, wave, lane, bias, 0,0,0, nullptr, nbase, g, &s, &sq); break;
    case 2: conv_work<5,false>(Ps, tk, wave, lane, bias, 0,0,0, nullptr, nbase, g, &s, &sq); break;
    default: conv_work<7,false>(Ps, tk, wave, lane, bias, 0,0,0, nullptr, nbase, g, &s, &sq); break;
  }
  red_s[wave][lane] = s; red_q[wave][lane] = sq;
  __syncthreads();
  if (wave == 0){
    float ts = red_s[0][lane]+red_s[1][lane]+red_s[2][lane]+red_s[3][lane];
    float tq = red_q[0][lane]+red_q[1][lane]+red_q[2][lane]+red_q[3][lane];
    atomicAdd(&stats[g*64 + lane], ts);
    atomicAdd(&stats[256 + g*64 + lane], tq);
  }
}

__global__ void k_bn_fin(const float* __restrict__ stats, const float* __restrict__ bn_g,
                         const float* __restrict__ bn_b, float* __restrict__ ss){
  int t = threadIdx.x;
  const float cnt = (float)(N_*L_);
  float m = stats[t]/cnt;
  float v = stats[256+t]/cnt - m*m;
  float sc = bn_g[t] / sqrtf(v + 1e-5f);
  ss[t] = sc; ss[256+t] = bn_b[t] - m*sc;
}

__global__ __launch_bounds__(256) void k_conv_apply(
    const int* __restrict__ tok, const float* __restrict__ P,
    const float* __restrict__ cb1, const float* __restrict__ cb3,
    const float* __restrict__ cb5, const float* __restrict__ cb7,
    const float* __restrict__ ss, const float* __restrict__ cnn_a_p,
    ushort* __restrict__ ynorm){
  const int g = blockIdx.y;
  const int nbase = blockIdx.x*16;
  const int tid = threadIdx.x, lane = tid & 63, wave = tid >> 6;
  const int ks = 2*g + 1, base = g*g;
  const float* cb = (g==0)?cb1:(g==1)?cb3:(g==2)?cb5:cb7;
  const float bias = cb[lane];
  const float scale = ss[g*64 + lane], shift = ss[256 + g*64 + lane];
  const float ca = cnn_a_p[0];
  __shared__ float Ps[7*2048];
  __shared__ int tk[16][L_];
  for (int i = tid; i < ks*512; i += 256)
    ((float4*)Ps)[i] = ((const float4*)(P + base*2048))[i];
  for (int i = tid; i < 16*L_; i += 256)
    tk[i>>5][i&31] = tok[(size_t)(nbase + (i>>5))*L_ + (i&31)];
  __syncthreads();
  float s, q;
  switch (g){
    case 0: conv_work<1,true>(Ps, tk, wave, lane, bias, scale, shift, ca, ynorm, nbase, g, &s, &q); break;
    case 1: conv_work<3,true>(Ps, tk, wave, lane, bias, scale, shift, ca, ynorm, nbase, g, &s, &q); break;
    case 2: conv_work<5,true>(Ps, tk, wave, lane, bias, scale, shift, ca, ynorm, nbase, g, &s, &q); break;
    default: conv_work<7,true>(Ps, tk, wave, lane, bias, scale, shift, ca, ynorm, nbase, g, &s, &q); break;
  }
}

// ---------------- GRU scan ----------------

// WxT3[c=g*256+u][k] = Wx[g][k][u], plain row-major bf16.
// WhT3s: swizzled for global_load_lds staging. Logical (kt b, row r=u*3+g, quad q, j):
//   value Wh[g][b*32+q*8+j][u] stored at phys ((b*768+r)*4 + (q ^ s(r)))*8 + j,
//   s(r) = (r&3)^((r>>2)&3)  -> 2-way-max LDS bank conflicts on frag reads.
__global__ void k_WT3(const float* __restrict__ Wx, const float* __restrict__ Wh,
                      ushort* __restrict__ WxT3, ushort* __restrict__ WhT3s){
  int id = blockIdx.x*256 + threadIdx.x;  // 0..196607
  {
    int g = id >> 16, k = (id >> 8) & 255, u = id & 255;
    WxT3[((size_t)(g*256 + u))*256 + k] = f2bf(Wx[(size_t)g*65536 + k*256 + u]);
  }
  {
    int j = id & 7, pq = (id >> 3) & 3, r = (id >> 5) % 768, b = id / 24576;
    int s = (r & 3) ^ ((r >> 2) & 3);
    int q = pq ^ s;
    int k = b*32 + q*8 + j;
    int u = r / 3, g = r - u*3;
    WhT3s[id] = f2bf(Wh[(size_t)g*65536 + k*256 + u]);
  }
}

// xp[row][c] = Y[row][:] @ WxT3[c][:], row = l_local*4096 + n, c = g*256+u.
// A-tile resident (staged once), bn-loop inside, transposed coalesced stores.
// grid 512, dynamic LDS 153600 B.
__global__ __launch_bounds__(256) void k_xproj(
    const ushort* __restrict__ Y, const ushort* __restrict__ WxT3,
    ushort* __restrict__ xp)
{
  extern __shared__ __align__(16) char smem[];
  ushort* As  = (ushort*)smem;            // [128][264]
  ushort* Bsx = (ushort*)smem + 33792;    // [128][264]
  ushort* Tb  = (ushort*)smem + 67584;    // [4][16][72]
  const int bm = blockIdx.x;
  const int tid = threadIdx.x, lane = tid & 63, w = tid >> 6;
  const int wm = w >> 1, wn = w & 1;
  const int quad = lane >> 4, l16 = lane & 15;
  #pragma unroll
  for (int i = 0; i < 16; ++i){
    int id = i*256 + tid;
    int row = id >> 5, cc = id & 31;
    *(uint4*)&As[row*264 + cc*8] = *(const uint4*)(Y + ((size_t)(bm*128 + row))*H_ + cc*8);
  }
  for (int bn = 0; bn < 6; ++bn){
    __syncthreads();
    #pragma unroll
    for (int i = 0; i < 16; ++i){
      int id = i*256 + tid;
      int row = id >> 5, cc = id & 31;
      *(uint4*)&Bsx[row*264 + cc*8] = *(const uint4*)(WxT3 + ((size_t)(bn*128 + row))*H_ + cc*8);
    }
    __syncthreads();
    floatx4 acc[4][4];
    #pragma unroll
    for (int i = 0; i < 4; ++i)
      #pragma unroll
      for (int j = 0; j < 4; ++j)
        acc[i][j] = (floatx4){0.f,0.f,0.f,0.f};
    #pragma unroll
    for (int kt = 0; kt < 8; ++kt){
      short8 a[4], b[4];
      #pragma unroll
      for (int mi = 0; mi < 4; ++mi)
        a[mi] = *(const short8*)&As[(wm*64 + mi*16 + l16)*264 + kt*32 + quad*8];
      #pragma unroll
      for (int ni = 0; ni < 4; ++ni)
        b[ni] = *(const short8*)&Bsx[(wn*64 + ni*16 + l16)*264 + kt*32 + quad*8];
      #pragma unroll
      for (int mi = 0; mi < 4; ++mi)
        #pragma unroll
        for (int ni = 0; ni < 4; ++ni)
          acc[mi][ni] = __builtin_amdgcn_mfma_f32_16x16x32_bf16(a[mi], b[ni], acc[mi][ni], 0,0,0);
    }
    ushort* Tw = Tb + w*16*72;
    #pragma unroll
    for (int mi = 0; mi < 4; ++mi){
      #pragma unroll
      for (int ni = 0; ni < 4; ++ni)
        #pragma unroll
        for (int r = 0; r < 4; ++r)
          Tw[(quad*4 + r)*72 + ni*16 + l16] = f2bf(acc[mi][ni][r]);
      // wave-internal LDS: per-wave in-order, no barrier needed
      #pragma unroll
      for (int i = 0; i < 2; ++i){
        int rr = i*8 + (lane >> 3);
        int cc = lane & 7;
        int grow = bm*128 + wm*64 + mi*16 + rr;
        *(uint4*)(xp + (size_t)grow*768 + bn*128 + wn*64 + cc*8) = *(const uint4*)&Tw[rr*72 + cc*8];
      }
    }
  }
}

// Persistent 16-step scan. grid 256 blocks; block owns rows n0..n0+15; h stays
// in regs (fp32) + LDS (bf16 A-frags). Per step stream Wh (393KB, L2) dbuf.
// dynamic LDS = 2*49152 + 16*264*2 = 106752 B.
__global__ __launch_bounds__(256) void k_scan(
    const ushort* __restrict__ WhT3s, const ushort* __restrict__ xp,
    const float* __restrict__ bx, const float* __restrict__ bh,
    const float* __restrict__ h_in, const ushort* __restrict__ hbf_in,
    float* __restrict__ h_out, ushort* __restrict__ hbf_out, int first)
{
  extern __shared__ __align__(16) char smem[];
  ushort* Bs0 = (ushort*)smem;              // 24576 ushorts (48KB)
  ushort* Bs1 = (ushort*)smem + 24576;      // 48KB
  ushort* hA  = (ushort*)smem + 49152;      // [16][264]
  float*  Ep  = (float*)smem;               // [16][768] aliases Bs0 exactly

  const int tid = threadIdx.x, lane = tid & 63, w = tid >> 6;
  const int quad = lane >> 4, l16 = lane & 15;
  const int n0 = blockIdx.x*16;
  const int u = tid;
  const int sw = (l16 & 3) ^ ((l16 >> 2) & 3);

  float hreg[16];
  if (first){
    #pragma unroll
    for (int r = 0; r < 16; ++r) hreg[r] = 0.f;
    for (int i = tid; i < 16*264; i += 256) hA[i] = 0;
  } else {
    #pragma unroll
    for (int r = 0; r < 16; ++r){
      hreg[r] = h_in[(size_t)(n0+r)*H_ + u];
      hA[r*264 + u] = hbf_in[(size_t)(n0+r)*H_ + u];
    }
  }
  const float b0 = bx[u] + bh[u];
  const float b1 = bx[256+u] + bh[256+u];
  const float b2x = bx[512+u], b2h = bh[512+u];

  for (int l = 0; l < 16; ++l){
    const ushort* xpl = xp + (size_t)l*N_*768;
    stage48(WhT3s, Bs0, w, lane);
    __syncthreads();
    floatx4 acc[12];
    #pragma unroll
    for (int i = 0; i < 12; ++i) acc[i] = (floatx4){0.f,0.f,0.f,0.f};
    for (int kt = 0; kt < 8; ++kt){
      if (kt < 7) stage48(WhT3s + (size_t)(kt+1)*24576, (kt & 1) ? Bs0 : Bs1, w, lane);
      const ushort* bcur = (kt & 1) ? Bs1 : Bs0;
      short8 a = *(const short8*)&hA[l16*264 + kt*32 + quad*8];
      #pragma unroll
      for (int ct = 0; ct < 12; ++ct){
        const int row = (w*12 + ct)*16 + l16;
        short8 b = *(const short8*)&bcur[row*32 + (quad ^ sw)*8];
        acc[ct] = __builtin_amdgcn_mfma_f32_16x16x32_bf16(a, b, acc[ct], 0,0,0);
      }
      __syncthreads();
    }
    // xp prefetch (in flight during Ep round-trip)
    float xrv[16], xzv[16], xnv[16];
    #pragma unroll
    for (int r = 0; r < 16; ++r){
      const ushort* q = xpl + (size_t)(n0+r)*768;
      xrv[r] = bf2f(q[u]); xzv[r] = bf2f(q[256+u]); xnv[r] = bf2f(q[512+u]);
    }
    #pragma unroll
    for (int ct = 0; ct < 12; ++ct){
      const int col = (w*12 + ct)*16 + l16;
      #pragma unroll
      for (int r = 0; r < 4; ++r)
        Ep[(quad*4 + r)*768 + col] = acc[ct][r];
    }
    __syncthreads();
    #pragma unroll
    for (int r = 0; r < 16; ++r){
      float hr = Ep[r*768 + u*3 + 0];
      float hz = Ep[r*768 + u*3 + 1];
      float hn = Ep[r*768 + u*3 + 2];
      float rg = sigmoid_f(xrv[r] + hr + b0);
      float zg = sigmoid_f(xzv[r] + hz + b1);
      float ng = tanhf(xnv[r] + b2x + rg*(hn + b2h));
      hreg[r] = ng*(1.f - zg) + hreg[r]*zg;
    }
    __syncthreads();   // Ep reads done before next step restages Bs0
    #pragma unroll
    for (int r = 0; r < 16; ++r) hA[r*264 + u] = f2bf(hreg[r]);
    // hA write -> next-step frag reads protected by next stage's __syncthreads
  }
  #pragma unroll
  for (int r = 0; r < 16; ++r){
    h_out[(size_t)(n0+r)*H_ + u] = hreg[r];
    hbf_out[(size_t)(n0+r)*H_ + u] = f2bf(hreg[r]);
  }
}

// c = prelu(prelu(h,a1) @ lin_W + lin_b, a2) -> out[..., 256:512]
__global__ __launch_bounds__(256) void k_final(
    const float* __restrict__ h, const float* __restrict__ a1p,
    const float* __restrict__ lin_W, const float* __restrict__ lin_b,
    const float* __restrict__ a2p, float* __restrict__ out){
  const int nbase = blockIdx.x*16, tid = threadIdx.x;
  __shared__ float hp[16][H_];
  const float a1 = a1p[0], a2 = a2p[0];
  for (int i = tid; i < 16*H_; i += 256)
    hp[i>>8][i&255] = prelu_f(h[(size_t)(nbase + (i>>8))*H_ + (i&255)], a1);
  __syncthreads();
  float acc[16];
  const float b = lin_b[tid];
  #pragma unroll
  for (int r = 0; r < 16; ++r) acc[r] = b;
  for (int j = 0; j < H_; ++j){
    float w = lin_W[(size_t)j*H_ + tid];
    #pragma unroll
    for (int r = 0; r < 16; ++r) acc[r] += hp[r][j]*w;
  }
  for (int r = 0; r < 16; ++r)
    out[(size_t)(nbase+r)*512 + 256 + tid] = prelu_f(acc[r], a2);
}

extern "C" void kernel_launch(void* const* d_in, const int* in_sizes, int n_in,
                              void* d_out, int out_size, void* d_ws, size_t ws_size,
                              hipStream_t stream) {
  (void)in_sizes; (void)n_in; (void)out_size; (void)ws_size;
  const float* obs      = (const float*)d_in[0];
  const float* comm     = (const float*)d_in[1];
  const float* obs_emb  = (const float*)d_in[2];
  const float* obs_a_emb= (const float*)d_in[3];
  const float* obs_W    = (const float*)d_in[4];
  const float* obs_b    = (const float*)d_in[5];
  const float* obs_a    = (const float*)d_in[6];
  const float* comm_emb = (const float*)d_in[7];
  const float* comm_a   = (const float*)d_in[8];
  const float* cw1      = (const float*)d_in[9];
  const float* cb1      = (const float*)d_in[10];
  const float* cw3      = (const float*)d_in[11];
  const float* cb3      = (const float*)d_in[12];
  const float* cw5      = (const float*)d_in[13];
  const float* cb5      = (const float*)d_in[14];
  const float* cw7      = (const float*)d_in[15];
  const float* cb7      = (const float*)d_in[16];
  const float* bn_g     = (const float*)d_in[17];
  const float* bn_b     = (const float*)d_in[18];
  const float* cnn_a    = (const float*)d_in[19];
  const float* Wx       = (const float*)d_in[20];
  const float* bx       = (const float*)d_in[21];
  const float* Wh       = (const float*)d_in[22];
  const float* bh       = (const float*)d_in[23];
  const float* lin_a1   = (const float*)d_in[24];
  const float* lin_W    = (const float*)d_in[25];
  const float* lin_b    = (const float*)d_in[26];
  const float* lin_a2   = (const float*)d_in[27];
  float* out = (float*)d_out;

  char* ws = (char*)d_ws;
  float*  contrib = (float*)(ws + 0);            // 4,194,304
  float*  P       = (float*)(ws + 4194304);      // 131,072
  int*    idx     = (int*)  (ws + 4325376);      // 524,288
  int*    tok     = (int*)  (ws + 4849664);      // 524,288
  float*  stats   = (float*)(ws + 5373952);      // 2,048
  float*  ss      = (float*)(ws + 5376000);      // 2,048
  ushort* WxT3    = (ushort*)(ws + 5378048);     // 393,216
  ushort* WhT3s   = (ushort*)(ws + 5771264);     // 393,216
  float*  h_a     = (float*)(ws + 6164480);      // 4,194,304
  float*  h_b     = (float*)(ws + 10358784);     // 4,194,304
  ushort* hbf_a   = (ushort*)(ws + 14553088);    // 2,097,152
  ushort* hbf_b   = (ushort*)(ws + 16650240);    // 2,097,152
  ushort* ynorm   = (ushort*)(ws + 18747392);    // 67,108,864
  ushort* xp      = (ushort*)(ws + 85856256);    // 100,663,296

  hipMemsetAsync(stats, 0, 512*sizeof(float), stream);

  k_idx<<<1024, 256, 0, stream>>>(obs, idx);
  k_tok<<<512, 256, 0, stream>>>(comm, tok);
  k_WT3<<<768, 256, 0, stream>>>(Wx, Wh, WxT3, WhT3s);
  k_P<<<dim3(16,32), 64, 0, stream>>>(comm_emb, comm_a, cw1, cw3, cw5, cw7, P);
  k_contrib<<<dim3(32,8), 256, 0, stream>>>(obs_emb, obs_a_emb, obs_W, contrib);
  k_obs_o<<<4096, 256, 0, stream>>>(idx, contrib, obs_b, obs_a, out);
  k_conv_stats<<<dim3(256,4), 256, 0, stream>>>(tok, P, cb1, cb3, cb5, cb7, stats);
  k_bn_fin<<<1, 256, 0, stream>>>(stats, bn_g, bn_b, ss);
  k_conv_apply<<<dim3(256,4), 256, 0, stream>>>(tok, P, cb1, cb3, cb5, cb7, ss, cnn_a, ynorm);

  // half 0: l = 0..15
  k_xproj<<<512, 256, 153600, stream>>>(ynorm, WxT3, xp);
  k_scan<<<256, 256, 106752, stream>>>(WhT3s, xp, bx, bh, h_a, hbf_a, h_a, hbf_a, 1);
  // half 1: l = 16..31
  k_xproj<<<512, 256, 153600, stream>>>(ynorm + (size_t)16*N_*H_, WxT3, xp);
  k_scan<<<256, 256, 106752, stream>>>(WhT3s, xp, bx, bh, h_a, hbf_a, h_b, hbf_b, 0);

  k_final<<<256, 256, 0, stream>>>(h_b, lin_a1, lin_W, lin_b, lin_a2, out);
}